// Round 1
// baseline (419.703 us; speedup 1.0000x reference)
//
#include <hip/hip_runtime.h>
#include <math.h>

#define BB 2
#define NN 384   // N1 == N2
#define DD 128   // D
#define HH 128   // H

__device__ __forceinline__ float sigmoidf_(float x) { return 1.f / (1.f + __expf(-x)); }

// ---------------------------------------------------------------- embed
// h1g = h1 @ node_W ; h2g = h2 @ node_W.  8 rows per block, 128 threads (one
// per output col) so each node_W load feeds 8 FMAs.
__global__ __launch_bounds__(128) void k_embed(
    const float* __restrict__ h1, const float* __restrict__ h2,
    const float* __restrict__ nW, float* __restrict__ h1g, float* __restrict__ h2g) {
  const int RT = 8;
  int r0 = blockIdx.x * RT;
  int c = threadIdx.x;
  const float* src; float* dst; int rb;
  if (r0 < BB * NN) { src = h1; dst = h1g; rb = r0; }
  else              { src = h2; dst = h2g; rb = r0 - BB * NN; }
  __shared__ float xs[RT][54];
  for (int idx = c; idx < RT * 54; idx += 128) xs[idx / 54][idx % 54] = src[rb * 54 + idx];
  __syncthreads();
  float acc[RT];
#pragma unroll
  for (int r = 0; r < RT; ++r) acc[r] = 0.f;
  for (int k = 0; k < 54; ++k) {
    float w = nW[k * DD + c];
#pragma unroll
    for (int r = 0; r < RT; ++r) acc[r] += xs[r][k] * w;
  }
#pragma unroll
  for (int r = 0; r < RT; ++r) dst[(rb + r) * DD + c] = acc[r];
}

// ---------------------------------------------------------------- GAT h & hA
// h = x@W + Wb ; hA = h@A  (hA only depends on own row's h -> fuse, h kept in LDS)
__global__ __launch_bounds__(128) void k_gat_hhA(
    const float* __restrict__ x, const float* __restrict__ W,
    const float* __restrict__ Wb, const float* __restrict__ A,
    float* __restrict__ h, float* __restrict__ hA) {
  const int RT = 8;
  int r0 = blockIdx.x * RT;
  int c = threadIdx.x;
  __shared__ float xs[RT][DD];
  __shared__ float hs[RT][DD];
#pragma unroll
  for (int r = 0; r < RT; ++r) xs[r][c] = x[(r0 + r) * DD + c];
  __syncthreads();
  float acc[RT];
  float bias = Wb[c];
#pragma unroll
  for (int r = 0; r < RT; ++r) acc[r] = bias;
  for (int k = 0; k < DD; ++k) {
    float w = W[k * DD + c];
#pragma unroll
    for (int r = 0; r < RT; ++r) acc[r] += xs[r][k] * w;
  }
#pragma unroll
  for (int r = 0; r < RT; ++r) { h[(r0 + r) * DD + c] = acc[r]; hs[r][c] = acc[r]; }
  __syncthreads();
#pragma unroll
  for (int r = 0; r < RT; ++r) acc[r] = 0.f;
  for (int k = 0; k < DD; ++k) {
    float a = A[k * DD + c];
#pragma unroll
    for (int r = 0; r < RT; ++r) acc[r] += hs[r][k] * a;
  }
#pragma unroll
  for (int r = 0; r < RT; ++r) hA[(r0 + r) * DD + c] = acc[r];
}

// ---------------------------------------------------------------- GAT attention
// e[j,k] = hA[j]·h[k] + h[j]·hA[k]; mask by adj; softmax over j (axis=1, i.e.
// per column k); att = softmax * adj.  Block: 4 columns k, 128 threads, each
// thread owns 3 j's. Column-wise max/sum block reductions via float4 LDS tree.
__global__ __launch_bounds__(128) void k_gat_att(
    const float* __restrict__ h, const float* __restrict__ hA,
    const float* __restrict__ adj, float* __restrict__ att) {
  const int KT = 4;
  int b = blockIdx.x / (NN / KT);
  int k0 = (blockIdx.x % (NN / KT)) * KT;
  int tid = threadIdx.x;
  __shared__ float hk[KT][DD];
  __shared__ float hAk[KT][DD];
#pragma unroll
  for (int q = 0; q < KT; ++q) {
    hk[q][tid]  = h [(b * NN + k0 + q) * DD + tid];
    hAk[q][tid] = hA[(b * NN + k0 + q) * DD + tid];
  }
  __syncthreads();
  float ev[3][KT], adjv[3][KT];
  float lmax[KT] = {-3e38f, -3e38f, -3e38f, -3e38f};
  for (int t = 0; t < 3; ++t) {
    int j = tid + t * 128;
    const float4* hj  = (const float4*)(h  + (b * NN + j) * DD);
    const float4* hAj = (const float4*)(hA + (b * NN + j) * DD);
    float e[KT] = {0.f, 0.f, 0.f, 0.f};
    for (int k4 = 0; k4 < DD / 4; ++k4) {
      float4 hv = hj[k4], av = hAj[k4];
#pragma unroll
      for (int q = 0; q < KT; ++q) {
        e[q] += av.x * hk[q][4 * k4 + 0] + av.y * hk[q][4 * k4 + 1]
              + av.z * hk[q][4 * k4 + 2] + av.w * hk[q][4 * k4 + 3]
              + hv.x * hAk[q][4 * k4 + 0] + hv.y * hAk[q][4 * k4 + 1]
              + hv.z * hAk[q][4 * k4 + 2] + hv.w * hAk[q][4 * k4 + 3];
      }
    }
    float4 areg = *(const float4*)(adj + (b * NN + j) * NN + k0);
    float a4[KT] = {areg.x, areg.y, areg.z, areg.w};
#pragma unroll
    for (int q = 0; q < KT; ++q) {
      adjv[t][q] = a4[q]; ev[t][q] = e[q];
      if (a4[q] > 0.f) lmax[q] = fmaxf(lmax[q], e[q]);
    }
  }
  __shared__ float4 red4[128];
  red4[tid] = make_float4(lmax[0], lmax[1], lmax[2], lmax[3]);
  __syncthreads();
  for (int s = 64; s > 0; s >>= 1) {
    if (tid < s) {
      float4 a = red4[tid], bq = red4[tid + s];
      red4[tid] = make_float4(fmaxf(a.x, bq.x), fmaxf(a.y, bq.y),
                              fmaxf(a.z, bq.z), fmaxf(a.w, bq.w));
    }
    __syncthreads();
  }
  float4 mx = red4[0];
  float m[KT] = {mx.x, mx.y, mx.z, mx.w};
  float lsum[KT] = {0.f, 0.f, 0.f, 0.f};
  for (int t = 0; t < 3; ++t) {
#pragma unroll
    for (int q = 0; q < KT; ++q) {
      float vx = (adjv[t][q] > 0.f) ? __expf(ev[t][q] - m[q]) : 0.f;
      ev[t][q] = vx; lsum[q] += vx;
    }
  }
  __syncthreads();  // all reads of red4[0] done before overwrite
  red4[tid] = make_float4(lsum[0], lsum[1], lsum[2], lsum[3]);
  __syncthreads();
  for (int s = 64; s > 0; s >>= 1) {
    if (tid < s) {
      float4 a = red4[tid], bq = red4[tid + s];
      red4[tid] = make_float4(a.x + bq.x, a.y + bq.y, a.z + bq.z, a.w + bq.w);
    }
    __syncthreads();
  }
  float4 dn = red4[0];
  float inv[KT] = {1.f / dn.x, 1.f / dn.y, 1.f / dn.z, 1.f / dn.w};
  for (int t = 0; t < 3; ++t) {
    int j = tid + t * 128;
    float4 w = make_float4(ev[t][0] * adjv[t][0] * inv[0], ev[t][1] * adjv[t][1] * inv[1],
                           ev[t][2] * adjv[t][2] * inv[2], ev[t][3] * adjv[t][3] * inv[3]);
    *(float4*)(att + (b * NN + j) * NN + k0) = w;
  }
}

// ---------------------------------------------------------------- GAT output + gate
// h_prime[i,c] = relu(sum_j att[i,j] h[j,c]); coeff = sigmoid([x,h']@gW + gb);
// out = coeff*x + (1-coeff)*h'.  8 rows i per block; att rows staged in LDS so
// each h[j,c] global load feeds 8 FMAs.
__global__ __launch_bounds__(128) void k_gat_out(
    const float* __restrict__ x, const float* __restrict__ h,
    const float* __restrict__ att, const float* __restrict__ gW,
    const float* __restrict__ gb, float* __restrict__ out) {
  const int IT = 8;
  int r0 = blockIdx.x * IT;  // global row b*NN+i
  int b = r0 / NN;
  int tid = threadIdx.x;
  __shared__ float arow[IT][NN];
  for (int idx = tid; idx < IT * NN; idx += 128) arow[idx / NN][idx % NN] = att[r0 * NN + idx];
  __syncthreads();
  float acc[IT];
#pragma unroll
  for (int r = 0; r < IT; ++r) acc[r] = 0.f;
  for (int j = 0; j < NN; ++j) {
    float hv = h[(b * NN + j) * DD + tid];
#pragma unroll
    for (int r = 0; r < IT; ++r) acc[r] += arow[r][j] * hv;
  }
  float g1 = gW[tid], g2 = gW[DD + tid], gbv = gb[0];
  __shared__ float redw[2];
#pragma unroll
  for (int r = 0; r < IT; ++r) {
    float hp = fmaxf(acc[r], 0.f);
    float xr = x[(r0 + r) * DD + tid];
    float v = xr * g1 + hp * g2;
#pragma unroll
    for (int off = 32; off > 0; off >>= 1) v += __shfl_down(v, off);
    if ((tid & 63) == 0) redw[tid >> 6] = v;
    __syncthreads();
    float coeff = sigmoidf_(redw[0] + redw[1] + gbv);
    out[(r0 + r) * DD + tid] = coeff * xr + (1.f - coeff) * hp;
    __syncthreads();  // protect redw before next r
  }
}

// ---------------------------------------------------------------- pair projections
// p1[row][m][h] = h1g[row]·W1[m][:D] + b1[m]   (bias folded into p1)
// p2[row][m][h] = h2g[row]·W1[m][D:]
__global__ __launch_bounds__(128) void k_pair_proj(
    const float* __restrict__ h1g, const float* __restrict__ h2g,
    const float* __restrict__ W1, const float* __restrict__ b1,
    float* __restrict__ p1, float* __restrict__ p2) {
  const int RT = 8;
  int m = blockIdx.x % 5;
  int r0 = (blockIdx.x / 5) * RT;
  int tid = threadIdx.x;
  bool lig = (r0 < BB * NN);
  const float* src = lig ? h1g : h2g;
  float* dst = lig ? p1 : p2;
  int rb = lig ? r0 : r0 - BB * NN;
  const float* W = W1 + (m * 256 + (lig ? 0 : 128)) * HH;
  __shared__ float xs[RT][DD];
#pragma unroll
  for (int r = 0; r < RT; ++r) xs[r][tid] = src[(rb + r) * DD + tid];
  __syncthreads();
  float acc[RT];
  float bias = lig ? b1[m * HH + tid] : 0.f;
#pragma unroll
  for (int r = 0; r < RT; ++r) acc[r] = bias;
  for (int k = 0; k < DD; ++k) {
    float w = W[k * HH + tid];
#pragma unroll
    for (int r = 0; r < RT; ++r) acc[r] += xs[r][k] * w;
  }
#pragma unroll
  for (int r = 0; r < RT; ++r) dst[((rb + r) * 5 + m) * HH + tid] = acc[r];
}

// ---------------------------------------------------------------- out init + e_u
__global__ void k_init_out(const float* __restrict__ delta_uff,
                           const float* __restrict__ duff_coeff, float* __restrict__ out) {
  int t = threadIdx.x;
  if (t < BB * 4) {
    int bb = t >> 2, c = t & 3;
    float v = 0.f;
    if (c == 2) v = duff_coeff[0] * duff_coeff[0] * delta_uff[bb];
    out[t] = v;
  }
}

// ---------------------------------------------------------------- pair energies
// Block: 4 ligand rows i × 384 threads (one per protein j). p1 rows (+b1), W2,
// b2 in LDS (broadcast reads). p2 row read float4, reused across the 4 i's.
__global__ __launch_bounds__(384) void k_pair_energy(
    const float* __restrict__ p1, const float* __restrict__ p2,
    const float* __restrict__ W2, const float* __restrict__ b2,
    const float* __restrict__ dmv, const float* __restrict__ charge1,
    const float* __restrict__ charge2, const float* __restrict__ veps,
    const float* __restrict__ vsig, const float* __restrict__ valid1,
    const float* __restrict__ valid2, const float* __restrict__ nm1,
    const float* __restrict__ nm2, const float* __restrict__ vdw_coeff,
    float* __restrict__ out) {
  const int TI = 4;
  int r0 = blockIdx.x * TI;  // global ligand row b*NN+i
  int b = r0 / NN;
  int j = threadIdx.x;
  __shared__ float p1s[TI][5 * HH];
  __shared__ float w2s[5 * HH];
  __shared__ float b2s[5];
  for (int idx = j; idx < TI * 5 * HH; idx += NN) p1s[idx / (5 * HH)][idx % (5 * HH)] = p1[r0 * 5 * HH + idx];
  for (int idx = j; idx < 5 * HH; idx += NN) w2s[idx] = W2[idx];
  if (j < 5) b2s[j] = b2[j];
  __syncthreads();

  float outm[TI][5];
  const float4* p2r = (const float4*)(p2 + (b * NN + j) * 5 * HH);
  for (int m = 0; m < 5; ++m) {
    float a0 = b2s[m], a1 = b2s[m], a2 = b2s[m], a3 = b2s[m];
#pragma unroll 4
    for (int h4 = 0; h4 < HH / 4; ++h4) {
      float4 v = p2r[m * (HH / 4) + h4];
      const float* w  = &w2s[m * HH + 4 * h4];
      const float* q0 = &p1s[0][m * HH + 4 * h4];
      const float* q1 = &p1s[1][m * HH + 4 * h4];
      const float* q2 = &p1s[2][m * HH + 4 * h4];
      const float* q3 = &p1s[3][m * HH + 4 * h4];
      a0 += fmaxf(q0[0] + v.x, 0.f) * w[0] + fmaxf(q0[1] + v.y, 0.f) * w[1]
          + fmaxf(q0[2] + v.z, 0.f) * w[2] + fmaxf(q0[3] + v.w, 0.f) * w[3];
      a1 += fmaxf(q1[0] + v.x, 0.f) * w[0] + fmaxf(q1[1] + v.y, 0.f) * w[1]
          + fmaxf(q1[2] + v.z, 0.f) * w[2] + fmaxf(q1[3] + v.w, 0.f) * w[3];
      a2 += fmaxf(q2[0] + v.x, 0.f) * w[0] + fmaxf(q2[1] + v.y, 0.f) * w[1]
          + fmaxf(q2[2] + v.z, 0.f) * w[2] + fmaxf(q2[3] + v.w, 0.f) * w[3];
      a3 += fmaxf(q3[0] + v.x, 0.f) * w[0] + fmaxf(q3[1] + v.y, 0.f) * w[1]
          + fmaxf(q3[2] + v.z, 0.f) * w[2] + fmaxf(q3[3] + v.w, 0.f) * w[3];
    }
    outm[0][m] = a0; outm[1][m] = a1; outm[2][m] = a2; outm[3][m] = a3;
  }

  float q2c = charge2[b * NN + j], v2 = valid2[b * NN + j], n2 = nm2[b * NN + j];
  float vc2 = vdw_coeff[0] * vdw_coeff[0];
  float ec_sum = 0.f, ev_sum = 0.f;
#pragma unroll
  for (int ti = 0; ti < TI; ++ti) {
    int gi = r0 + ti;
    int pidx = gi * NN + j;
    float dx = dmv[pidx * 3 + 0], dy = dmv[pidx * 3 + 1], dz = dmv[pidx * 3 + 2];
    float dm = sqrtf(dx * dx + dy * dy + dz * dz + 1e-10f);
    if (dm < 0.5f) dm = 1e10f;
    // coulomb
    float cA = sigmoidf_(outm[ti][0]);
    float cN = sigmoidf_(outm[ti][1]) * 2.f + 1.f;
    float e_c = cA * charge1[gi] * q2c * __powf(1.f / dm, cN);
    e_c *= valid1[gi] * v2;
    e_c = fminf(fmaxf(e_c, -100.f), 100.f);
    ec_sum += e_c;
    // vdw
    float vA = (sigmoidf_(outm[ti][2]) * 0.6f + 0.7f) * vc2 * veps[pidx];
    float vB = tanhf(outm[ti][3]) * 0.6f + 0.7f;
    float vN = sigmoidf_(outm[ti][4]) * 2.f + 5.f;
    float dm0 = vsig[pidx] * vB;
    if (dm0 < 1e-4f) dm0 = 1.f;
    float rr = __powf(dm0 / dm, vN);
    float e_v = vA * (rr * rr - 2.f * rr);
    e_v *= nm1[gi] * n2;
    e_v = fminf(e_v, 100.f);
    ev_sum += e_v;
  }
#pragma unroll
  for (int off = 32; off > 0; off >>= 1) {
    ec_sum += __shfl_down(ec_sum, off);
    ev_sum += __shfl_down(ev_sum, off);
  }
  __shared__ float rec[6], rev[6];
  if ((j & 63) == 0) { rec[j >> 6] = ec_sum; rev[j >> 6] = ev_sum; }
  __syncthreads();
  if (j == 0) {
    float a = 0.f, c = 0.f;
    for (int w = 0; w < 6; ++w) { a += rec[w]; c += rev[w]; }
    atomicAdd(&out[b * 4 + 0], a);
    atomicAdd(&out[b * 4 + 1], c);
  }
}

// ---------------------------------------------------------------- intercept
__global__ __launch_bounds__(128) void k_intercept(
    const float* __restrict__ h1g, const float* __restrict__ valid1,
    const float* __restrict__ W1, const float* __restrict__ b1,
    const float* __restrict__ W2, const float* __restrict__ b2, float* __restrict__ out) {
  int b = blockIdx.x;
  int tid = threadIdx.x;
  __shared__ float hs[DD];
  float acc = 0.f;
  for (int i = 0; i < NN; ++i) acc += h1g[(b * NN + i) * DD + tid] * valid1[b * NN + i];
  hs[tid] = acc;
  __syncthreads();
  float hid = b1[tid];
  for (int c = 0; c < DD; ++c) hid += hs[c] * W1[c * HH + tid];
  hid = fmaxf(hid, 0.f);
  float v = hid * W2[tid];
#pragma unroll
  for (int off = 32; off > 0; off >>= 1) v += __shfl_down(v, off);
  __shared__ float redw[2];
  if ((tid & 63) == 0) redw[tid >> 6] = v;
  __syncthreads();
  if (tid == 0) out[b * 4 + 3] = redw[0] + redw[1] + b2[0];
}

// ---------------------------------------------------------------- launch
extern "C" void kernel_launch(void* const* d_in, const int* in_sizes, int n_in,
                              void* d_out, int out_size, void* d_ws, size_t ws_size,
                              hipStream_t stream) {
  (void)in_sizes; (void)n_in; (void)out_size; (void)ws_size;
  // setup_inputs() dict order:
  const float* h1         = (const float*)d_in[0];
  const float* h2         = (const float*)d_in[1];
  const float* adj1       = (const float*)d_in[2];
  const float* dmv        = (const float*)d_in[3];
  const float* charge1    = (const float*)d_in[4];
  const float* charge2    = (const float*)d_in[5];
  const float* veps       = (const float*)d_in[6];
  const float* vsig       = (const float*)d_in[7];
  const float* delta_uff  = (const float*)d_in[8];
  const float* valid1     = (const float*)d_in[9];
  const float* valid2     = (const float*)d_in[10];
  const float* nm1        = (const float*)d_in[11];
  const float* nm2        = (const float*)d_in[12];
  const float* node_W     = (const float*)d_in[13];
  const float* gat_W      = (const float*)d_in[14];
  const float* gat_Wb     = (const float*)d_in[15];
  const float* gat_A      = (const float*)d_in[16];
  const float* gat_gW     = (const float*)d_in[17];
  const float* gat_gb     = (const float*)d_in[18];
  const float* pW1        = (const float*)d_in[19];
  const float* pb1        = (const float*)d_in[20];
  const float* pW2        = (const float*)d_in[21];
  const float* pb2        = (const float*)d_in[22];
  const float* vdw_coeff  = (const float*)d_in[23];
  const float* duff_coeff = (const float*)d_in[24];
  const float* iW1        = (const float*)d_in[25];
  const float* ib1        = (const float*)d_in[26];
  const float* iW2        = (const float*)d_in[27];
  const float* ib2        = (const float*)d_in[28];
  float* out = (float*)d_out;

  // workspace layout (floats): 5*98304 + 294912 + 2*491520 = 1,769,472 fl ≈ 6.75 MB
  float* ws = (float*)d_ws;
  const int RN = BB * NN * DD;  // 98304
  float* h1gA  = ws;
  float* h1gB  = h1gA + RN;
  float* h2g   = h1gB + RN;
  float* hbuf  = h2g + RN;
  float* hAbuf = hbuf + RN;
  float* att   = hAbuf + RN;               // BB*NN*NN
  float* p1    = att + BB * NN * NN;       // BB*NN*5*HH
  float* p2    = p1 + BB * NN * 5 * HH;

  k_embed<<<dim3(2 * BB * NN / 8), dim3(128), 0, stream>>>(h1, h2, node_W, h1gA, h2g);

  float* cur = h1gA;
  float* nxt = h1gB;
  for (int l = 0; l < 3; ++l) {
    k_gat_hhA<<<dim3(BB * NN / 8), dim3(128), 0, stream>>>(
        cur, gat_W + l * DD * DD, gat_Wb + l * DD, gat_A + l * DD * DD, hbuf, hAbuf);
    k_gat_att<<<dim3(BB * NN / 4), dim3(128), 0, stream>>>(hbuf, hAbuf, adj1, att);
    k_gat_out<<<dim3(BB * NN / 8), dim3(128), 0, stream>>>(
        cur, hbuf, att, gat_gW + l * 2 * DD, gat_gb + l, nxt);
    float* t = cur; cur = nxt; nxt = t;
  }
  const float* h1gF = cur;  // final ligand features

  k_pair_proj<<<dim3((2 * BB * NN / 8) * 5), dim3(128), 0, stream>>>(h1gF, h2g, pW1, pb1, p1, p2);
  k_init_out<<<dim3(1), dim3(64), 0, stream>>>(delta_uff, duff_coeff, out);
  k_pair_energy<<<dim3(BB * NN / 4), dim3(NN), 0, stream>>>(
      p1, p2, pW2, pb2, dmv, charge1, charge2, veps, vsig,
      valid1, valid2, nm1, nm2, vdw_coeff, out);
  k_intercept<<<dim3(BB), dim3(128), 0, stream>>>(h1gF, valid1, iW1, ib1, iW2, ib2, out);
}

// Round 2
// 398.469 us; speedup vs baseline: 1.0533x; 1.0533x over previous
//
#include <hip/hip_runtime.h>
#include <math.h>

#define BB 2
#define NN 384   // N1 == N2
#define DD 128   // D
#define HH 128   // H

__device__ __forceinline__ float sigmoidf_(float x) { return 1.f / (1.f + __expf(-x)); }
__device__ __forceinline__ float tanhf_(float x)    { return 1.f - 2.f / (__expf(2.f * x) + 1.f); }

// ---------------------------------------------------------------- embed
// h1g = h1 @ node_W ; h2g = h2 @ node_W.  4 rows per block -> 384 blocks.
__global__ __launch_bounds__(128) void k_embed(
    const float* __restrict__ h1, const float* __restrict__ h2,
    const float* __restrict__ nW, float* __restrict__ h1g, float* __restrict__ h2g) {
  const int RT = 4;
  int r0 = blockIdx.x * RT;
  int c = threadIdx.x;
  const float* src; float* dst; int rb;
  if (r0 < BB * NN) { src = h1; dst = h1g; rb = r0; }
  else              { src = h2; dst = h2g; rb = r0 - BB * NN; }
  __shared__ float xs[RT][54];
  for (int idx = c; idx < RT * 54; idx += 128) xs[idx / 54][idx % 54] = src[rb * 54 + idx];
  __syncthreads();
  float acc[RT] = {0.f, 0.f, 0.f, 0.f};
  for (int k = 0; k < 54; ++k) {
    float w = nW[k * DD + c];
#pragma unroll
    for (int r = 0; r < RT; ++r) acc[r] += xs[r][k] * w;
  }
#pragma unroll
  for (int r = 0; r < RT; ++r) dst[(rb + r) * DD + c] = acc[r];
}

// ---------------------------------------------------------------- GAT h & hA
// h = x@W + Wb ; hA = h@A.  2 rows per block -> 384 blocks.
__global__ __launch_bounds__(128) void k_gat_hhA(
    const float* __restrict__ x, const float* __restrict__ W,
    const float* __restrict__ Wb, const float* __restrict__ A,
    float* __restrict__ h, float* __restrict__ hA) {
  const int RT = 2;
  int r0 = blockIdx.x * RT;
  int c = threadIdx.x;
  __shared__ float xs[RT][DD];
  __shared__ float hs[RT][DD];
#pragma unroll
  for (int r = 0; r < RT; ++r) xs[r][c] = x[(r0 + r) * DD + c];
  __syncthreads();
  float bias = Wb[c];
  float a0 = bias, a1 = bias;
#pragma unroll 4
  for (int k = 0; k < DD; ++k) {
    float w = W[k * DD + c];
    a0 += xs[0][k] * w; a1 += xs[1][k] * w;
  }
  h[(r0 + 0) * DD + c] = a0; hs[0][c] = a0;
  h[(r0 + 1) * DD + c] = a1; hs[1][c] = a1;
  __syncthreads();
  a0 = 0.f; a1 = 0.f;
#pragma unroll 4
  for (int k = 0; k < DD; ++k) {
    float a = A[k * DD + c];
    a0 += hs[0][k] * a; a1 += hs[1][k] * a;
  }
  hA[(r0 + 0) * DD + c] = a0;
  hA[(r0 + 1) * DD + c] = a1;
}

// ---------------------------------------------------------------- GAT attention
// e[j,k] = hA[j]·h[k] + h[j]·hA[k]; softmax over j per column k; att = sm*adj.
// Block: 2 columns, 128 threads, 3 j's per thread -> 384 blocks. Shfl reductions.
__global__ __launch_bounds__(128) void k_gat_att(
    const float* __restrict__ h, const float* __restrict__ hA,
    const float* __restrict__ adj, float* __restrict__ att) {
  const int KT = 2;
  int b = blockIdx.x / (NN / KT);
  int k0 = (blockIdx.x % (NN / KT)) * KT;
  int tid = threadIdx.x;
  __shared__ float hk[KT][DD];
  __shared__ float hAk[KT][DD];
#pragma unroll
  for (int q = 0; q < KT; ++q) {
    hk[q][tid]  = h [(b * NN + k0 + q) * DD + tid];
    hAk[q][tid] = hA[(b * NN + k0 + q) * DD + tid];
  }
  __syncthreads();
  const float4* hk0  = (const float4*)hk[0];
  const float4* hk1  = (const float4*)hk[1];
  const float4* hA0  = (const float4*)hAk[0];
  const float4* hA1  = (const float4*)hAk[1];
  float ev[3][KT], adjv[3][KT];
  float lmax[KT] = {-3e38f, -3e38f};
  for (int t = 0; t < 3; ++t) {
    int j = tid + t * 128;
    const float4* hj  = (const float4*)(h  + (b * NN + j) * DD);
    const float4* hAj = (const float4*)(hA + (b * NN + j) * DD);
    float e0 = 0.f, e1 = 0.f;
#pragma unroll 4
    for (int k4 = 0; k4 < DD / 4; ++k4) {
      float4 hv = hj[k4], av = hAj[k4];
      float4 c0 = hk0[k4], d0 = hA0[k4], c1 = hk1[k4], d1 = hA1[k4];
      e0 += av.x * c0.x + av.y * c0.y + av.z * c0.z + av.w * c0.w
          + hv.x * d0.x + hv.y * d0.y + hv.z * d0.z + hv.w * d0.w;
      e1 += av.x * c1.x + av.y * c1.y + av.z * c1.z + av.w * c1.w
          + hv.x * d1.x + hv.y * d1.y + hv.z * d1.z + hv.w * d1.w;
    }
    float2 areg = *(const float2*)(adj + (b * NN + j) * NN + k0);
    adjv[t][0] = areg.x; adjv[t][1] = areg.y;
    ev[t][0] = e0; ev[t][1] = e1;
    if (areg.x > 0.f) lmax[0] = fmaxf(lmax[0], e0);
    if (areg.y > 0.f) lmax[1] = fmaxf(lmax[1], e1);
  }
  // column-wise max across 128 threads: shfl within wave, LDS across 2 waves
#pragma unroll
  for (int off = 32; off > 0; off >>= 1) {
    lmax[0] = fmaxf(lmax[0], __shfl_down(lmax[0], off));
    lmax[1] = fmaxf(lmax[1], __shfl_down(lmax[1], off));
  }
  __shared__ float cmx[2][KT];
  if ((tid & 63) == 0) { cmx[tid >> 6][0] = lmax[0]; cmx[tid >> 6][1] = lmax[1]; }
  __syncthreads();
  float m0 = fmaxf(cmx[0][0], cmx[1][0]);
  float m1 = fmaxf(cmx[0][1], cmx[1][1]);
  float s0 = 0.f, s1 = 0.f;
  for (int t = 0; t < 3; ++t) {
    float v0 = (adjv[t][0] > 0.f) ? __expf(ev[t][0] - m0) : 0.f;
    float v1 = (adjv[t][1] > 0.f) ? __expf(ev[t][1] - m1) : 0.f;
    ev[t][0] = v0; ev[t][1] = v1; s0 += v0; s1 += v1;
  }
#pragma unroll
  for (int off = 32; off > 0; off >>= 1) {
    s0 += __shfl_down(s0, off);
    s1 += __shfl_down(s1, off);
  }
  __shared__ float csm[2][KT];
  if ((tid & 63) == 0) { csm[tid >> 6][0] = s0; csm[tid >> 6][1] = s1; }
  __syncthreads();
  float inv0 = 1.f / (csm[0][0] + csm[1][0]);
  float inv1 = 1.f / (csm[0][1] + csm[1][1]);
  for (int t = 0; t < 3; ++t) {
    int j = tid + t * 128;
    float2 w = make_float2(ev[t][0] * adjv[t][0] * inv0, ev[t][1] * adjv[t][1] * inv1);
    *(float2*)(att + (b * NN + j) * NN + k0) = w;
  }
}

// ---------------------------------------------------------------- GAT output + gate
// h_prime[i,c] = relu(sum_j att[i,j] h[j,c]); gated residual. 2 rows -> 384 blocks.
__global__ __launch_bounds__(128) void k_gat_out(
    const float* __restrict__ x, const float* __restrict__ h,
    const float* __restrict__ att, const float* __restrict__ gW,
    const float* __restrict__ gb, float* __restrict__ out) {
  const int IT = 2;
  int r0 = blockIdx.x * IT;  // global row b*NN+i
  int b = r0 / NN;
  int tid = threadIdx.x;
  __shared__ float arow[IT][NN];
  for (int idx = tid; idx < IT * NN; idx += 128) arow[idx / NN][idx % NN] = att[r0 * NN + idx];
  __syncthreads();
  float acc0 = 0.f, acc1 = 0.f;
#pragma unroll 4
  for (int j = 0; j < NN; ++j) {
    float hv = h[(b * NN + j) * DD + tid];
    acc0 += arow[0][j] * hv;
    acc1 += arow[1][j] * hv;
  }
  float g1 = gW[tid], g2 = gW[DD + tid], gbv = gb[0];
  float accs[IT] = {acc0, acc1};
  __shared__ float redw[2];
#pragma unroll
  for (int r = 0; r < IT; ++r) {
    float hp = fmaxf(accs[r], 0.f);
    float xr = x[(r0 + r) * DD + tid];
    float v = xr * g1 + hp * g2;
#pragma unroll
    for (int off = 32; off > 0; off >>= 1) v += __shfl_down(v, off);
    if ((tid & 63) == 0) redw[tid >> 6] = v;
    __syncthreads();
    float coeff = sigmoidf_(redw[0] + redw[1] + gbv);
    out[(r0 + r) * DD + tid] = coeff * xr + (1.f - coeff) * hp;
    __syncthreads();  // protect redw before next r
  }
}

// ---------------------------------------------------------------- pair projections
// p1[row][m][h] = h1g[row]·W1[m][:D] + b1[m] ; p2[row][m][h] = h2g[row]·W1[m][D:]
// Also zero-inits d_out and writes the e_u term (block 0).
__global__ __launch_bounds__(128) void k_pair_proj(
    const float* __restrict__ h1g, const float* __restrict__ h2g,
    const float* __restrict__ W1, const float* __restrict__ b1,
    const float* __restrict__ delta_uff, const float* __restrict__ duff_coeff,
    float* __restrict__ p1, float* __restrict__ p2, float* __restrict__ out) {
  const int RT = 8;
  int m = blockIdx.x % 5;
  int r0 = (blockIdx.x / 5) * RT;
  int tid = threadIdx.x;
  if (blockIdx.x == 0 && tid < BB * 4) {
    int bb = tid >> 2, c = tid & 3;
    out[tid] = (c == 2) ? duff_coeff[0] * duff_coeff[0] * delta_uff[bb] : 0.f;
  }
  bool lig = (r0 < BB * NN);
  const float* src = lig ? h1g : h2g;
  float* dst = lig ? p1 : p2;
  int rb = lig ? r0 : r0 - BB * NN;
  const float* W = W1 + (m * 256 + (lig ? 0 : 128)) * HH;
  __shared__ float xs[RT][DD];
#pragma unroll
  for (int r = 0; r < RT; ++r) xs[r][tid] = src[(rb + r) * DD + tid];
  __syncthreads();
  float acc[RT];
  float bias = lig ? b1[m * HH + tid] : 0.f;
#pragma unroll
  for (int r = 0; r < RT; ++r) acc[r] = bias;
  for (int k = 0; k < DD; ++k) {
    float w = W[k * HH + tid];
#pragma unroll
    for (int r = 0; r < RT; ++r) acc[r] += xs[r][k] * w;
  }
#pragma unroll
  for (int r = 0; r < RT; ++r) dst[((rb + r) * 5 + m) * HH + tid] = acc[r];
}

// ---------------------------------------------------------------- pair energies
// Block: TI=2 ligand rows × TJ=192 protein cols (192 threads) -> 768 blocks.
// p1 rows (+b1 folded), W2, b2 in LDS (broadcast). p2 row float4 from L2.
__global__ __launch_bounds__(192) void k_pair_energy(
    const float* __restrict__ p1, const float* __restrict__ p2,
    const float* __restrict__ W2, const float* __restrict__ b2,
    const float* __restrict__ dmv, const float* __restrict__ charge1,
    const float* __restrict__ charge2, const float* __restrict__ veps,
    const float* __restrict__ vsig, const float* __restrict__ valid1,
    const float* __restrict__ valid2, const float* __restrict__ nm1,
    const float* __restrict__ nm2, const float* __restrict__ vdw_coeff,
    float* __restrict__ out) {
  const int TI = 2;
  int tile = blockIdx.x >> 1;
  int jhalf = blockIdx.x & 1;
  int r0 = tile * TI;        // global ligand row b*NN+i
  int b = r0 / NN;
  int tid = threadIdx.x;
  int j = jhalf * 192 + tid;
  __shared__ float p1s[TI][5 * HH];
  __shared__ float w2s[5 * HH];
  __shared__ float b2s[5];
  for (int idx = tid; idx < TI * 5 * HH; idx += 192) p1s[idx / (5 * HH)][idx % (5 * HH)] = p1[r0 * 5 * HH + idx];
  for (int idx = tid; idx < 5 * HH; idx += 192) w2s[idx] = W2[idx];
  if (tid < 5) b2s[tid] = b2[tid];
  __syncthreads();

  float outm[TI][5];
  const float4* p2r = (const float4*)(p2 + (b * NN + j) * 5 * HH);
  for (int m = 0; m < 5; ++m) {
    const float4* w4 = (const float4*)(w2s + m * HH);
    const float4* q0 = (const float4*)(p1s[0] + m * HH);
    const float4* q1 = (const float4*)(p1s[1] + m * HH);
    float a0 = b2s[m], a1 = b2s[m];
#pragma unroll 4
    for (int h4 = 0; h4 < HH / 4; ++h4) {
      float4 v = p2r[m * (HH / 4) + h4];
      float4 w = w4[h4];
      float4 x0 = q0[h4], x1 = q1[h4];
      a0 += fmaxf(x0.x + v.x, 0.f) * w.x + fmaxf(x0.y + v.y, 0.f) * w.y
          + fmaxf(x0.z + v.z, 0.f) * w.z + fmaxf(x0.w + v.w, 0.f) * w.w;
      a1 += fmaxf(x1.x + v.x, 0.f) * w.x + fmaxf(x1.y + v.y, 0.f) * w.y
          + fmaxf(x1.z + v.z, 0.f) * w.z + fmaxf(x1.w + v.w, 0.f) * w.w;
    }
    outm[0][m] = a0; outm[1][m] = a1;
  }

  float q2c = charge2[b * NN + j], v2 = valid2[b * NN + j], n2 = nm2[b * NN + j];
  float vc2 = vdw_coeff[0] * vdw_coeff[0];
  float ec_sum = 0.f, ev_sum = 0.f;
#pragma unroll
  for (int ti = 0; ti < TI; ++ti) {
    int gi = r0 + ti;
    int pidx = gi * NN + j;
    float dx = dmv[pidx * 3 + 0], dy = dmv[pidx * 3 + 1], dz = dmv[pidx * 3 + 2];
    float dm = sqrtf(dx * dx + dy * dy + dz * dz + 1e-10f);
    if (dm < 0.5f) dm = 1e10f;
    // coulomb
    float cA = sigmoidf_(outm[ti][0]);
    float cN = sigmoidf_(outm[ti][1]) * 2.f + 1.f;
    float e_c = cA * charge1[gi] * q2c * __powf(1.f / dm, cN);
    e_c *= valid1[gi] * v2;
    e_c = fminf(fmaxf(e_c, -100.f), 100.f);
    ec_sum += e_c;
    // vdw
    float vA = (sigmoidf_(outm[ti][2]) * 0.6f + 0.7f) * vc2 * veps[pidx];
    float vB = tanhf_(outm[ti][3]) * 0.6f + 0.7f;
    float vN = sigmoidf_(outm[ti][4]) * 2.f + 5.f;
    float dm0 = vsig[pidx] * vB;
    if (dm0 < 1e-4f) dm0 = 1.f;
    float rr = __powf(dm0 / dm, vN);
    float e_v = vA * (rr * rr - 2.f * rr);
    e_v *= nm1[gi] * n2;
    e_v = fminf(e_v, 100.f);
    ev_sum += e_v;
  }
#pragma unroll
  for (int off = 32; off > 0; off >>= 1) {
    ec_sum += __shfl_down(ec_sum, off);
    ev_sum += __shfl_down(ev_sum, off);
  }
  __shared__ float rec[3], rev[3];
  if ((tid & 63) == 0) { rec[tid >> 6] = ec_sum; rev[tid >> 6] = ev_sum; }
  __syncthreads();
  if (tid == 0) {
    atomicAdd(&out[b * 4 + 0], rec[0] + rec[1] + rec[2]);
    atomicAdd(&out[b * 4 + 1], rev[0] + rev[1] + rev[2]);
  }
}

// ---------------------------------------------------------------- intercept
// hs = sum_i h1g[i]*valid1[i]; out = relu(hs@W1+b1)@W2 + b2. 256 thr, i-split 2.
__global__ __launch_bounds__(256) void k_intercept(
    const float* __restrict__ h1g, const float* __restrict__ valid1,
    const float* __restrict__ W1, const float* __restrict__ b1,
    const float* __restrict__ W2, const float* __restrict__ b2, float* __restrict__ out) {
  int b = blockIdx.x;
  int tid = threadIdx.x;
  int c = tid & 127, g = tid >> 7;
  float acc = 0.f;
  for (int i = g * 192; i < (g + 1) * 192; ++i)
    acc += h1g[(b * NN + i) * DD + c] * valid1[b * NN + i];
  __shared__ float hp[2][DD];
  __shared__ float hsf[DD];
  __shared__ float redw[2];
  hp[g][c] = acc;
  __syncthreads();
  if (tid < 128) hsf[tid] = hp[0][tid] + hp[1][tid];
  __syncthreads();
  if (tid < 128) {
    float hid = b1[tid];
#pragma unroll 4
    for (int k = 0; k < DD; ++k) hid += hsf[k] * W1[k * HH + tid];
    hid = fmaxf(hid, 0.f);
    float v = hid * W2[tid];
#pragma unroll
    for (int off = 32; off > 0; off >>= 1) v += __shfl_down(v, off);
    if ((tid & 63) == 0) redw[tid >> 6] = v;
  }
  __syncthreads();
  if (tid == 0) out[b * 4 + 3] = redw[0] + redw[1] + b2[0];
}

// ---------------------------------------------------------------- launch
extern "C" void kernel_launch(void* const* d_in, const int* in_sizes, int n_in,
                              void* d_out, int out_size, void* d_ws, size_t ws_size,
                              hipStream_t stream) {
  (void)in_sizes; (void)n_in; (void)out_size; (void)ws_size;
  const float* h1         = (const float*)d_in[0];
  const float* h2         = (const float*)d_in[1];
  const float* adj1       = (const float*)d_in[2];
  const float* dmv        = (const float*)d_in[3];
  const float* charge1    = (const float*)d_in[4];
  const float* charge2    = (const float*)d_in[5];
  const float* veps       = (const float*)d_in[6];
  const float* vsig       = (const float*)d_in[7];
  const float* delta_uff  = (const float*)d_in[8];
  const float* valid1     = (const float*)d_in[9];
  const float* valid2     = (const float*)d_in[10];
  const float* nm1        = (const float*)d_in[11];
  const float* nm2        = (const float*)d_in[12];
  const float* node_W     = (const float*)d_in[13];
  const float* gat_W      = (const float*)d_in[14];
  const float* gat_Wb     = (const float*)d_in[15];
  const float* gat_A      = (const float*)d_in[16];
  const float* gat_gW     = (const float*)d_in[17];
  const float* gat_gb     = (const float*)d_in[18];
  const float* pW1        = (const float*)d_in[19];
  const float* pb1        = (const float*)d_in[20];
  const float* pW2        = (const float*)d_in[21];
  const float* pb2        = (const float*)d_in[22];
  const float* vdw_coeff  = (const float*)d_in[23];
  const float* duff_coeff = (const float*)d_in[24];
  const float* iW1        = (const float*)d_in[25];
  const float* ib1        = (const float*)d_in[26];
  const float* iW2        = (const float*)d_in[27];
  const float* ib2        = (const float*)d_in[28];
  float* out = (float*)d_out;

  float* ws = (float*)d_ws;
  const int RN = BB * NN * DD;  // 98304
  float* h1gA  = ws;
  float* h1gB  = h1gA + RN;
  float* h2g   = h1gB + RN;
  float* hbuf  = h2g + RN;
  float* hAbuf = hbuf + RN;
  float* att   = hAbuf + RN;               // BB*NN*NN
  float* p1    = att + BB * NN * NN;       // BB*NN*5*HH
  float* p2    = p1 + BB * NN * 5 * HH;

  k_embed<<<dim3(2 * BB * NN / 4), dim3(128), 0, stream>>>(h1, h2, node_W, h1gA, h2g);

  float* cur = h1gA;
  float* nxt = h1gB;
  for (int l = 0; l < 3; ++l) {
    k_gat_hhA<<<dim3(BB * NN / 2), dim3(128), 0, stream>>>(
        cur, gat_W + l * DD * DD, gat_Wb + l * DD, gat_A + l * DD * DD, hbuf, hAbuf);
    k_gat_att<<<dim3(BB * NN / 2), dim3(128), 0, stream>>>(hbuf, hAbuf, adj1, att);
    k_gat_out<<<dim3(BB * NN / 2), dim3(128), 0, stream>>>(
        cur, hbuf, att, gat_gW + l * 2 * DD, gat_gb + l, nxt);
    float* t = cur; cur = nxt; nxt = t;
  }
  const float* h1gF = cur;

  k_pair_proj<<<dim3((2 * BB * NN / 8) * 5), dim3(128), 0, stream>>>(
      h1gF, h2g, pW1, pb1, delta_uff, duff_coeff, p1, p2, out);
  k_pair_energy<<<dim3((BB * NN / 2) * 2), dim3(192), 0, stream>>>(
      p1, p2, pW2, pb2, dmv, charge1, charge2, veps, vsig,
      valid1, valid2, nm1, nm2, vdw_coeff, out);
  k_intercept<<<dim3(BB), dim3(256), 0, stream>>>(h1gF, valid1, iW1, ib1, iW2, ib2, out);
}

// Round 3
// 392.131 us; speedup vs baseline: 1.0703x; 1.0162x over previous
//
#include <hip/hip_runtime.h>
#include <math.h>

#define BB 2
#define NN 384   // N1 == N2
#define DD 128   // D
#define HH 128   // H

__device__ __forceinline__ float sigmoidf_(float x) { return 1.f / (1.f + __expf(-x)); }
__device__ __forceinline__ float tanhf_(float x)    { return 1.f - 2.f / (__expf(2.f * x) + 1.f); }

// ---------------------------------------------------------------- embed
// h1g = h1 @ node_W ; h2g = h2 @ node_W.  2 rows per block, 256 thr -> 768 blocks.
__global__ __launch_bounds__(256) void k_embed(
    const float* __restrict__ h1, const float* __restrict__ h2,
    const float* __restrict__ nW, float* __restrict__ h1g, float* __restrict__ h2g) {
  int r0 = blockIdx.x * 2;
  int tid = threadIdx.x;
  const float* src; float* dst; int rb;
  if (r0 < BB * NN) { src = h1; dst = h1g; rb = r0; }
  else              { src = h2; dst = h2g; rb = r0 - BB * NN; }
  __shared__ float xs[2][54];
  if (tid < 108) xs[tid / 54][tid % 54] = src[rb * 54 + tid];
  __syncthreads();
  int rr = tid >> 7, c = tid & 127;
  float acc = 0.f;
#pragma unroll 6
  for (int k = 0; k < 54; ++k) acc += xs[rr][k] * nW[k * DD + c];
  dst[(rb + rr) * DD + c] = acc;
}

// ---------------------------------------------------------------- GAT h & hA
// 1 row per block, k-split 2 across 256 thr -> 768 blocks. h = x@W+Wb; hA = h@A.
__global__ __launch_bounds__(256) void k_gat_hhA(
    const float* __restrict__ x, const float* __restrict__ W,
    const float* __restrict__ Wb, const float* __restrict__ A,
    float* __restrict__ h, float* __restrict__ hA) {
  int r = blockIdx.x;
  int tid = threadIdx.x, c = tid & 127, kh = tid >> 7;
  __shared__ float xs[DD], hs[DD];
  __shared__ float ph[2][DD];
  if (tid < DD) xs[tid] = x[r * DD + tid];
  __syncthreads();
  float acc = 0.f;
  const float* Wp = W + (kh * 64) * DD + c;
#pragma unroll 4
  for (int k = 0; k < 64; ++k) acc += xs[kh * 64 + k] * Wp[k * DD];
  ph[kh][c] = acc;
  __syncthreads();
  if (tid < DD) {
    float hv = ph[0][tid] + ph[1][tid] + Wb[tid];
    h[r * DD + tid] = hv; hs[tid] = hv;
  }
  __syncthreads();
  acc = 0.f;
  const float* Ap = A + (kh * 64) * DD + c;
#pragma unroll 4
  for (int k = 0; k < 64; ++k) acc += hs[kh * 64 + k] * Ap[k * DD];
  ph[kh][c] = acc;
  __syncthreads();
  if (tid < DD) hA[r * DD + tid] = ph[0][tid] + ph[1][tid];
}

// ---------------------------------------------------------------- GAT attention
// 1 softmax column per block -> 768 blocks, 256 thr.  Thread owns j=tid and
// (tid<128) j=256+tid. e[j,k]=hA[j]·h[k]+h[j]·hA[k], masked softmax over j.
__global__ __launch_bounds__(256) void k_gat_att(
    const float* __restrict__ h, const float* __restrict__ hA,
    const float* __restrict__ adj, float* __restrict__ att) {
  int col = blockIdx.x;          // b*NN + k
  int b = col / NN, k = col % NN;
  int tid = threadIdx.x;
  __shared__ float hk[DD], hAk[DD];
  __shared__ float rmx[4], rsm[4];
  if (tid < DD) { hk[tid] = h[col * DD + tid]; hAk[tid] = hA[col * DD + tid]; }
  __syncthreads();
  int j1 = tid;
  bool has2 = (tid < NN - 256);  // tid < 128
  int j2 = has2 ? (256 + tid) : 0;
  float a1 = adj[(b * NN + j1) * NN + k];
  float a2 = has2 ? adj[(b * NN + j2) * NN + k] : 0.f;
  const float4* h1p  = (const float4*)(h  + (b * NN + j1) * DD);
  const float4* hA1p = (const float4*)(hA + (b * NN + j1) * DD);
  const float4* h2p  = (const float4*)(h  + (b * NN + j2) * DD);
  const float4* hA2p = (const float4*)(hA + (b * NN + j2) * DD);
  const float4* hk4  = (const float4*)hk;
  const float4* hAk4 = (const float4*)hAk;
  float e1 = 0.f, e2 = 0.f;
#pragma unroll 4
  for (int q = 0; q < DD / 4; ++q) {
    float4 ck = hk4[q], dk = hAk4[q];
    float4 hv1 = h1p[q], av1 = hA1p[q];
    e1 += av1.x * ck.x + av1.y * ck.y + av1.z * ck.z + av1.w * ck.w
        + hv1.x * dk.x + hv1.y * dk.y + hv1.z * dk.z + hv1.w * dk.w;
    float4 hv2 = h2p[q], av2 = hA2p[q];
    e2 += av2.x * ck.x + av2.y * ck.y + av2.z * ck.z + av2.w * ck.w
        + hv2.x * dk.x + hv2.y * dk.y + hv2.z * dk.z + hv2.w * dk.w;
  }
  float lmax = -3e38f;
  if (a1 > 0.f) lmax = e1;
  if (has2 && a2 > 0.f) lmax = fmaxf(lmax, e2);
#pragma unroll
  for (int off = 32; off > 0; off >>= 1) lmax = fmaxf(lmax, __shfl_down(lmax, off));
  if ((tid & 63) == 0) rmx[tid >> 6] = lmax;
  __syncthreads();
  float m = fmaxf(fmaxf(rmx[0], rmx[1]), fmaxf(rmx[2], rmx[3]));
  float v1 = (a1 > 0.f) ? __expf(e1 - m) : 0.f;
  float v2 = (has2 && a2 > 0.f) ? __expf(e2 - m) : 0.f;
  float s = v1 + v2;
#pragma unroll
  for (int off = 32; off > 0; off >>= 1) s += __shfl_down(s, off);
  if ((tid & 63) == 0) rsm[tid >> 6] = s;
  __syncthreads();
  float inv = 1.f / (rsm[0] + rsm[1] + rsm[2] + rsm[3]);
  att[(b * NN + j1) * NN + k] = v1 * a1 * inv;
  if (has2) att[(b * NN + j2) * NN + k] = v2 * a2 * inv;
}

// ---------------------------------------------------------------- GAT output + gate
// 1 row per block, j-split 2 across 256 thr -> 768 blocks.
__global__ __launch_bounds__(256) void k_gat_out(
    const float* __restrict__ x, const float* __restrict__ h,
    const float* __restrict__ att, const float* __restrict__ gW,
    const float* __restrict__ gb, float* __restrict__ out) {
  int r = blockIdx.x;            // b*NN + i
  int b = r / NN;
  int tid = threadIdx.x, c = tid & 127, jh = tid >> 7;
  __shared__ float arow[NN];
  __shared__ float ph[2][DD];
  __shared__ float redw[2];
  for (int idx = tid; idx < NN; idx += 256) arow[idx] = att[r * NN + idx];
  __syncthreads();
  float acc = 0.f;
  const float* hp = h + (b * NN + jh * 192) * DD + c;
#pragma unroll 4
  for (int jj = 0; jj < 192; ++jj) acc += arow[jh * 192 + jj] * hp[jj * DD];
  ph[jh][c] = acc;
  __syncthreads();
  if (tid < DD) {
    float hpr = fmaxf(ph[0][tid] + ph[1][tid], 0.f);
    float xr = x[r * DD + tid];
    float v = xr * gW[tid] + hpr * gW[DD + tid];
#pragma unroll
    for (int off = 32; off > 0; off >>= 1) v += __shfl_down(v, off);
    if ((tid & 63) == 0) redw[tid >> 6] = v;
  }
  __syncthreads();
  if (tid < DD) {
    float hpr = fmaxf(ph[0][tid] + ph[1][tid], 0.f);
    float xr = x[r * DD + tid];
    float coeff = sigmoidf_(redw[0] + redw[1] + gb[0]);
    out[r * DD + tid] = coeff * xr + (1.f - coeff) * hpr;
  }
}

// ---------------------------------------------------------------- pair projections
// 16 rows × 1 m per block, k-split 2 -> 480 blocks. Block 0 also inits d_out.
__global__ __launch_bounds__(256) void k_pair_proj(
    const float* __restrict__ h1g, const float* __restrict__ h2g,
    const float* __restrict__ W1, const float* __restrict__ b1,
    const float* __restrict__ delta_uff, const float* __restrict__ duff_coeff,
    float* __restrict__ p1, float* __restrict__ p2, float* __restrict__ out) {
  const int RT = 16;
  int m = blockIdx.x % 5;
  int r0 = (blockIdx.x / 5) * RT;
  int tid = threadIdx.x, c = tid & 127, kh = tid >> 7;
  if (blockIdx.x == 0 && tid < BB * 4) {
    int bb = tid >> 2, cc = tid & 3;
    out[tid] = (cc == 2) ? duff_coeff[0] * duff_coeff[0] * delta_uff[bb] : 0.f;
  }
  bool lig = (r0 < BB * NN);
  const float* src = lig ? h1g : h2g;
  float* dst = lig ? p1 : p2;
  int rb = lig ? r0 : r0 - BB * NN;
  const float* W = W1 + (m * 256 + (lig ? 0 : 128)) * HH;
  __shared__ float xs[RT][DD];
  __shared__ float ps[RT][DD];
  for (int idx = tid; idx < RT * DD; idx += 256) xs[idx >> 7][idx & 127] = src[rb * DD + idx];
  __syncthreads();
  float acc[RT];
#pragma unroll
  for (int r = 0; r < RT; ++r) acc[r] = 0.f;
  const float* Wp = W + (kh * 64) * HH + c;
#pragma unroll 2
  for (int k = 0; k < 64; ++k) {
    float w = Wp[k * HH];
#pragma unroll
    for (int r = 0; r < RT; ++r) acc[r] += xs[r][kh * 64 + k] * w;
  }
  if (kh == 1) {
#pragma unroll
    for (int r = 0; r < RT; ++r) ps[r][c] = acc[r];
  }
  __syncthreads();
  if (kh == 0) {
    float bias = lig ? b1[m * HH + c] : 0.f;
#pragma unroll
    for (int r = 0; r < RT; ++r)
      dst[((rb + r) * 5 + m) * HH + c] = acc[r] + ps[r][c] + bias;
  }
}

// ---------------------------------------------------------------- pair energies
// Blocks 0..767: TI=2 rows × 192-j half, 192 thr. Inner loop h4-outer/m-inner:
// 5 independent p2 loads in flight per h4, 48 VALU ops each batch.
// Blocks 768..775: intercept partial row-sums into ws_int.
__global__ __launch_bounds__(192) void k_pair_energy(
    const float* __restrict__ p1, const float* __restrict__ p2,
    const float* __restrict__ W2, const float* __restrict__ b2,
    const float* __restrict__ dmv, const float* __restrict__ charge1,
    const float* __restrict__ charge2, const float* __restrict__ veps,
    const float* __restrict__ vsig, const float* __restrict__ valid1,
    const float* __restrict__ valid2, const float* __restrict__ nm1,
    const float* __restrict__ nm2, const float* __restrict__ vdw_coeff,
    const float* __restrict__ h1g, float* __restrict__ ws_int,
    float* __restrict__ out) {
  int tid = threadIdx.x;
  if (blockIdx.x >= 768) {  // ---- intercept partials: 8 blocks, 96 i-rows each
    int eb = blockIdx.x - 768;
    int b = eb >> 2, ch = eb & 3;
    if (tid < DD) {
      float acc = 0.f;
      int i0 = ch * 96;
#pragma unroll 4
      for (int i = 0; i < 96; ++i) {
        int gi = b * NN + i0 + i;
        acc += h1g[gi * DD + tid] * valid1[gi];
      }
      ws_int[eb * DD + tid] = acc;
    }
    return;
  }
  const int TI = 2;
  int tile = blockIdx.x >> 1, jh = blockIdx.x & 1;
  int r0 = tile * TI;
  int b = r0 / NN;
  int j = jh * 192 + tid;
  __shared__ float p1s[TI * 5 * HH];   // 1280 fl
  __shared__ float w2s[5 * HH];
  __shared__ float b2s[5];
  __shared__ float rec[3], rev[3];
  for (int idx = tid; idx < TI * 5 * HH; idx += 192) p1s[idx] = p1[r0 * 5 * HH + idx];
  for (int idx = tid; idx < 5 * HH; idx += 192) w2s[idx] = W2[idx];
  if (tid < 5) b2s[tid] = b2[tid];
  __syncthreads();

  const float4* p2r = (const float4*)(p2 + (b * NN + j) * 5 * HH);
  const float4* q0 = (const float4*)(p1s);
  const float4* q1 = (const float4*)(p1s + 5 * HH);
  const float4* w4 = (const float4*)(w2s);
  float acc0[5], acc1[5];
#pragma unroll
  for (int m = 0; m < 5; ++m) { acc0[m] = b2s[m]; acc1[m] = b2s[m]; }
#pragma unroll 2
  for (int h4 = 0; h4 < HH / 4; ++h4) {
    float4 v[5];
#pragma unroll
    for (int m = 0; m < 5; ++m) v[m] = p2r[m * (HH / 4) + h4];
#pragma unroll
    for (int m = 0; m < 5; ++m) {
      float4 x0 = q0[m * (HH / 4) + h4];
      float4 x1 = q1[m * (HH / 4) + h4];
      float4 w = w4[m * (HH / 4) + h4];
      acc0[m] += fmaxf(x0.x + v[m].x, 0.f) * w.x + fmaxf(x0.y + v[m].y, 0.f) * w.y
               + fmaxf(x0.z + v[m].z, 0.f) * w.z + fmaxf(x0.w + v[m].w, 0.f) * w.w;
      acc1[m] += fmaxf(x1.x + v[m].x, 0.f) * w.x + fmaxf(x1.y + v[m].y, 0.f) * w.y
               + fmaxf(x1.z + v[m].z, 0.f) * w.z + fmaxf(x1.w + v[m].w, 0.f) * w.w;
    }
  }

  float q2c = charge2[b * NN + j], v2 = valid2[b * NN + j], n2 = nm2[b * NN + j];
  float vc2 = vdw_coeff[0] * vdw_coeff[0];
  float ec_sum = 0.f, ev_sum = 0.f;
#pragma unroll
  for (int ti = 0; ti < TI; ++ti) {
    const float* am = ti ? acc1 : acc0;
    int gi = r0 + ti;
    int pidx = gi * NN + j;
    float dx = dmv[pidx * 3 + 0], dy = dmv[pidx * 3 + 1], dz = dmv[pidx * 3 + 2];
    float dm = sqrtf(dx * dx + dy * dy + dz * dz + 1e-10f);
    if (dm < 0.5f) dm = 1e10f;
    // coulomb
    float cA = sigmoidf_(am[0]);
    float cN = sigmoidf_(am[1]) * 2.f + 1.f;
    float e_c = cA * charge1[gi] * q2c * __powf(1.f / dm, cN);
    e_c *= valid1[gi] * v2;
    e_c = fminf(fmaxf(e_c, -100.f), 100.f);
    ec_sum += e_c;
    // vdw
    float vA = (sigmoidf_(am[2]) * 0.6f + 0.7f) * vc2 * veps[pidx];
    float vB = tanhf_(am[3]) * 0.6f + 0.7f;
    float vN = sigmoidf_(am[4]) * 2.f + 5.f;
    float dm0 = vsig[pidx] * vB;
    if (dm0 < 1e-4f) dm0 = 1.f;
    float rr = __powf(dm0 / dm, vN);
    float e_v = vA * (rr * rr - 2.f * rr);
    e_v *= nm1[gi] * n2;
    e_v = fminf(e_v, 100.f);
    ev_sum += e_v;
  }
#pragma unroll
  for (int off = 32; off > 0; off >>= 1) {
    ec_sum += __shfl_down(ec_sum, off);
    ev_sum += __shfl_down(ev_sum, off);
  }
  if ((tid & 63) == 0) { rec[tid >> 6] = ec_sum; rev[tid >> 6] = ev_sum; }
  __syncthreads();
  if (tid == 0) {
    atomicAdd(&out[b * 4 + 0], rec[0] + rec[1] + rec[2]);
    atomicAdd(&out[b * 4 + 1], rev[0] + rev[1] + rev[2]);
  }
}

// ---------------------------------------------------------------- intercept finish
__global__ __launch_bounds__(256) void k_intercept_fin(
    const float* __restrict__ ws_int, const float* __restrict__ W1,
    const float* __restrict__ b1, const float* __restrict__ W2,
    const float* __restrict__ b2, float* __restrict__ out) {
  int b = blockIdx.x;
  int tid = threadIdx.x, c = tid & 127, kh = tid >> 7;
  __shared__ float hsf[DD];
  __shared__ float ph[2][DD];
  __shared__ float redw[2];
  if (tid < DD)
    hsf[tid] = ws_int[(b * 4 + 0) * DD + tid] + ws_int[(b * 4 + 1) * DD + tid]
             + ws_int[(b * 4 + 2) * DD + tid] + ws_int[(b * 4 + 3) * DD + tid];
  __syncthreads();
  float acc = 0.f;
  const float* Wp = W1 + (kh * 64) * HH + c;
#pragma unroll 4
  for (int k = 0; k < 64; ++k) acc += hsf[kh * 64 + k] * Wp[k * HH];
  ph[kh][c] = acc;
  __syncthreads();
  if (tid < DD) {
    float hid = fmaxf(ph[0][tid] + ph[1][tid] + b1[tid], 0.f);
    float v = hid * W2[tid];
#pragma unroll
    for (int off = 32; off > 0; off >>= 1) v += __shfl_down(v, off);
    if ((tid & 63) == 0) redw[tid >> 6] = v;
  }
  __syncthreads();
  if (tid == 0) out[b * 4 + 3] = redw[0] + redw[1] + b2[0];
}

// ---------------------------------------------------------------- launch
extern "C" void kernel_launch(void* const* d_in, const int* in_sizes, int n_in,
                              void* d_out, int out_size, void* d_ws, size_t ws_size,
                              hipStream_t stream) {
  (void)in_sizes; (void)n_in; (void)out_size; (void)ws_size;
  const float* h1         = (const float*)d_in[0];
  const float* h2         = (const float*)d_in[1];
  const float* adj1       = (const float*)d_in[2];
  const float* dmv        = (const float*)d_in[3];
  const float* charge1    = (const float*)d_in[4];
  const float* charge2    = (const float*)d_in[5];
  const float* veps       = (const float*)d_in[6];
  const float* vsig       = (const float*)d_in[7];
  const float* delta_uff  = (const float*)d_in[8];
  const float* valid1     = (const float*)d_in[9];
  const float* valid2     = (const float*)d_in[10];
  const float* nm1        = (const float*)d_in[11];
  const float* nm2        = (const float*)d_in[12];
  const float* node_W     = (const float*)d_in[13];
  const float* gat_W      = (const float*)d_in[14];
  const float* gat_Wb     = (const float*)d_in[15];
  const float* gat_A      = (const float*)d_in[16];
  const float* gat_gW     = (const float*)d_in[17];
  const float* gat_gb     = (const float*)d_in[18];
  const float* pW1        = (const float*)d_in[19];
  const float* pb1        = (const float*)d_in[20];
  const float* pW2        = (const float*)d_in[21];
  const float* pb2        = (const float*)d_in[22];
  const float* vdw_coeff  = (const float*)d_in[23];
  const float* duff_coeff = (const float*)d_in[24];
  const float* iW1        = (const float*)d_in[25];
  const float* ib1        = (const float*)d_in[26];
  const float* iW2        = (const float*)d_in[27];
  const float* ib2        = (const float*)d_in[28];
  float* out = (float*)d_out;

  float* ws = (float*)d_ws;
  const int RN = BB * NN * DD;  // 98304
  float* h1gA   = ws;
  float* h1gB   = h1gA + RN;
  float* h2g    = h1gB + RN;
  float* hbuf   = h2g + RN;
  float* hAbuf  = hbuf + RN;
  float* att    = hAbuf + RN;               // BB*NN*NN
  float* p1     = att + BB * NN * NN;       // BB*NN*5*HH
  float* p2     = p1 + BB * NN * 5 * HH;
  float* ws_int = p2 + BB * NN * 5 * HH;    // 8*128

  k_embed<<<dim3(2 * BB * NN / 2), dim3(256), 0, stream>>>(h1, h2, node_W, h1gA, h2g);

  float* cur = h1gA;
  float* nxt = h1gB;
  for (int l = 0; l < 3; ++l) {
    k_gat_hhA<<<dim3(BB * NN), dim3(256), 0, stream>>>(
        cur, gat_W + l * DD * DD, gat_Wb + l * DD, gat_A + l * DD * DD, hbuf, hAbuf);
    k_gat_att<<<dim3(BB * NN), dim3(256), 0, stream>>>(hbuf, hAbuf, adj1, att);
    k_gat_out<<<dim3(BB * NN), dim3(256), 0, stream>>>(
        cur, hbuf, att, gat_gW + l * 2 * DD, gat_gb + l, nxt);
    float* t = cur; cur = nxt; nxt = t;
  }
  const float* h1gF = cur;

  k_pair_proj<<<dim3((2 * BB * NN / 16) * 5), dim3(256), 0, stream>>>(
      h1gF, h2g, pW1, pb1, delta_uff, duff_coeff, p1, p2, out);
  k_pair_energy<<<dim3(768 + 8), dim3(192), 0, stream>>>(
      p1, p2, pW2, pb2, dmv, charge1, charge2, veps, vsig,
      valid1, valid2, nm1, nm2, vdw_coeff, h1gF, ws_int, out);
  k_intercept_fin<<<dim3(BB), dim3(256), 0, stream>>>(ws_int, iW1, ib1, iW2, ib2, out);
}

// Round 4
// 325.713 us; speedup vs baseline: 1.2886x; 1.2039x over previous
//
#include <hip/hip_runtime.h>
#include <math.h>

#define BB 2
#define NN 384   // N1 == N2
#define DD 128   // D
#define HH 128   // H
#define RT_ALL (BB * NN)        // 768 rows per side
#define PCOLS (BB * NN)         // 768: width of transposed layouts

__device__ __forceinline__ float sigmoidf_(float x) { return 1.f / (1.f + __expf(-x)); }
__device__ __forceinline__ float tanhf_(float x)    { return 1.f - 2.f / (__expf(2.f * x) + 1.f); }

// ---------------------------------------------------------------- embed
// h1g = h1 @ node_W ; h2g = h2 @ node_W.  2 rows per block, 256 thr -> 768 blocks.
__global__ __launch_bounds__(256) void k_embed(
    const float* __restrict__ h1, const float* __restrict__ h2,
    const float* __restrict__ nW, float* __restrict__ h1g, float* __restrict__ h2g) {
  int r0 = blockIdx.x * 2;
  int tid = threadIdx.x;
  const float* src; float* dst; int rb;
  if (r0 < RT_ALL) { src = h1; dst = h1g; rb = r0; }
  else             { src = h2; dst = h2g; rb = r0 - RT_ALL; }
  __shared__ float xs[2][54];
  if (tid < 108) xs[tid / 54][tid % 54] = src[rb * 54 + tid];
  __syncthreads();
  int rr = tid >> 7, c = tid & 127;
  float acc = 0.f;
#pragma unroll 6
  for (int k = 0; k < 54; ++k) acc += xs[rr][k] * nW[k * DD + c];
  dst[(rb + rr) * DD + c] = acc;
}

// ---------------------------------------------------------------- GAT h & hA
// 1 row per block, k-split 2 across 256 thr -> 768 blocks.
// Writes h, hA row-major AND hT, hAT transposed ([c][row], width 768).
__global__ __launch_bounds__(256) void k_gat_hhA(
    const float* __restrict__ x, const float* __restrict__ W,
    const float* __restrict__ Wb, const float* __restrict__ A,
    float* __restrict__ h, float* __restrict__ hA,
    float* __restrict__ hT, float* __restrict__ hAT) {
  int r = blockIdx.x;
  int tid = threadIdx.x, c = tid & 127, kh = tid >> 7;
  __shared__ float xs[DD], hs[DD];
  __shared__ float ph[2][DD];
  if (tid < DD) xs[tid] = x[r * DD + tid];
  __syncthreads();
  float acc = 0.f;
  const float* Wp = W + (kh * 64) * DD + c;
#pragma unroll 4
  for (int k = 0; k < 64; ++k) acc += xs[kh * 64 + k] * Wp[k * DD];
  ph[kh][c] = acc;
  __syncthreads();
  if (tid < DD) {
    float hv = ph[0][tid] + ph[1][tid] + Wb[tid];
    h[r * DD + tid] = hv; hT[tid * PCOLS + r] = hv; hs[tid] = hv;
  }
  __syncthreads();
  acc = 0.f;
  const float* Ap = A + (kh * 64) * DD + c;
#pragma unroll 4
  for (int k = 0; k < 64; ++k) acc += hs[kh * 64 + k] * Ap[k * DD];
  ph[kh][c] = acc;
  __syncthreads();
  if (tid < DD) {
    float av = ph[0][tid] + ph[1][tid];
    hA[r * DD + tid] = av; hAT[tid * PCOLS + r] = av;
  }
}

// ---------------------------------------------------------------- GAT attention
// One softmax column q=k per block -> 768 blocks, 384 thr (lane = j).
// e[j,k] = hA[j]·h[k] + h[j]·hA[k] read via transposed hT/hAT (coalesced over j)
// and uniform h[k]/hA[k] rows (s_load). adj is symmetric -> read adj[k][j]
// coalesced. Stores attT[q][p] coalesced.
__global__ __launch_bounds__(384) void k_gat_att(
    const float* __restrict__ h, const float* __restrict__ hA,
    const float* __restrict__ hT, const float* __restrict__ hAT,
    const float* __restrict__ adj, float* __restrict__ attT) {
  int col = blockIdx.x;          // b*NN + k
  int b = col / NN;
  int tid = threadIdx.x;         // j
  const float* hrow  = h  + col * DD;   // uniform
  const float* hArow = hA + col * DD;   // uniform
  const float* hTb  = hT  + b * NN + tid;
  const float* hATb = hAT + b * NN + tid;
  float e = 0.f;
#pragma unroll 8
  for (int c = 0; c < DD; ++c)
    e += hATb[c * PCOLS] * hrow[c] + hTb[c * PCOLS] * hArow[c];
  float a = adj[col * NN + tid];  // == adj[(b*NN+j)*NN+k] by symmetry
  __shared__ float rmx[6], rsm[6];
  float lmax = (a > 0.f) ? e : -3e38f;
#pragma unroll
  for (int off = 32; off > 0; off >>= 1) lmax = fmaxf(lmax, __shfl_down(lmax, off));
  if ((tid & 63) == 0) rmx[tid >> 6] = lmax;
  __syncthreads();
  float m = fmaxf(fmaxf(fmaxf(rmx[0], rmx[1]), fmaxf(rmx[2], rmx[3])), fmaxf(rmx[4], rmx[5]));
  float v = (a > 0.f) ? __expf(e - m) : 0.f;
  float s = v;
#pragma unroll
  for (int off = 32; off > 0; off >>= 1) s += __shfl_down(s, off);
  if ((tid & 63) == 0) rsm[tid >> 6] = s;
  __syncthreads();
  float inv = 1.f / (rsm[0] + rsm[1] + rsm[2] + rsm[3] + rsm[4] + rsm[5]);
  attT[col * NN + tid] = v * a * inv;
}

// ---------------------------------------------------------------- GAT output + gate
// 1 row i per block, j-split 2 across 256 thr -> 768 blocks. att row staged
// from attT (strided reads, L2-reused across blocks).
__global__ __launch_bounds__(256) void k_gat_out(
    const float* __restrict__ x, const float* __restrict__ h,
    const float* __restrict__ attT, const float* __restrict__ gW,
    const float* __restrict__ gb, float* __restrict__ out) {
  int r = blockIdx.x;            // b*NN + i
  int b = r / NN, i = r - b * NN;
  int tid = threadIdx.x, c = tid & 127, jh = tid >> 7;
  __shared__ float arow[NN];
  __shared__ float ph[2][DD];
  __shared__ float redw[2];
  for (int idx = tid; idx < NN; idx += 256) arow[idx] = attT[(b * NN + idx) * NN + i];
  __syncthreads();
  float acc = 0.f;
  const float* hp = h + (b * NN + jh * 192) * DD + c;
#pragma unroll 4
  for (int jj = 0; jj < 192; ++jj) acc += arow[jh * 192 + jj] * hp[jj * DD];
  ph[jh][c] = acc;
  __syncthreads();
  if (tid < DD) {
    float hpr = fmaxf(ph[0][tid] + ph[1][tid], 0.f);
    float xr = x[r * DD + tid];
    float v = xr * gW[tid] + hpr * gW[DD + tid];
#pragma unroll
    for (int off = 32; off > 0; off >>= 1) v += __shfl_down(v, off);
    if ((tid & 63) == 0) redw[tid >> 6] = v;
  }
  __syncthreads();
  if (tid < DD) {
    float hpr = fmaxf(ph[0][tid] + ph[1][tid], 0.f);
    float xr = x[r * DD + tid];
    float coeff = sigmoidf_(redw[0] + redw[1] + gb[0]);
    out[r * DD + tid] = coeff * xr + (1.f - coeff) * hpr;
  }
}

// ---------------------------------------------------------------- pair projections
// 16 rows × 1 m per block, k-split 2 -> 480 blocks. Ligand -> p1 row-major
// (bias folded). Protein -> p2T transposed [m][h][row]. Block 0 inits d_out.
__global__ __launch_bounds__(256) void k_pair_proj(
    const float* __restrict__ h1g, const float* __restrict__ h2g,
    const float* __restrict__ W1, const float* __restrict__ b1,
    const float* __restrict__ delta_uff, const float* __restrict__ duff_coeff,
    float* __restrict__ p1, float* __restrict__ p2T, float* __restrict__ out) {
  const int RT = 16;
  int m = blockIdx.x % 5;
  int r0 = (blockIdx.x / 5) * RT;
  int tid = threadIdx.x, c = tid & 127, kh = tid >> 7;
  if (blockIdx.x == 0 && tid < BB * 4) {
    int bb = tid >> 2, cc = tid & 3;
    out[tid] = (cc == 2) ? duff_coeff[0] * duff_coeff[0] * delta_uff[bb] : 0.f;
  }
  bool lig = (r0 < RT_ALL);
  const float* src = lig ? h1g : h2g;
  int rb = lig ? r0 : r0 - RT_ALL;
  const float* W = W1 + (m * 256 + (lig ? 0 : 128)) * HH;
  __shared__ float xs[RT][DD];
  __shared__ float ps[RT][DD];
  for (int idx = tid; idx < RT * DD; idx += 256) xs[idx >> 7][idx & 127] = src[rb * DD + idx];
  __syncthreads();
  float acc[RT];
#pragma unroll
  for (int r = 0; r < RT; ++r) acc[r] = 0.f;
  const float* Wp = W + (kh * 64) * HH + c;
#pragma unroll 2
  for (int k = 0; k < 64; ++k) {
    float w = Wp[k * HH];
#pragma unroll
    for (int r = 0; r < RT; ++r) acc[r] += xs[r][kh * 64 + k] * w;
  }
  if (kh == 1) {
#pragma unroll
    for (int r = 0; r < RT; ++r) ps[r][c] = acc[r];
  }
  __syncthreads();
  if (kh == 0) {
    if (lig) {
      float bias = b1[m * HH + c];
#pragma unroll
      for (int r = 0; r < RT; ++r)
        p1[((rb + r) * 5 + m) * HH + c] = acc[r] + ps[r][c] + bias;
    } else {
      float* dst = p2T + (m * HH + c) * PCOLS + rb;
#pragma unroll
      for (int q = 0; q < RT / 4; ++q) {
        float4 v = make_float4(acc[4 * q + 0] + ps[4 * q + 0][c],
                               acc[4 * q + 1] + ps[4 * q + 1][c],
                               acc[4 * q + 2] + ps[4 * q + 2][c],
                               acc[4 * q + 3] + ps[4 * q + 3][c]);
        *(float4*)(dst + 4 * q) = v;
      }
    }
  }
}

// ---------------------------------------------------------------- pair energies
// Blocks 0..767: TI=2 ligand rows × 192-j half, 192 thr, lane = j.
// p2T loads coalesced over lanes; p1/W2/b2 wave-uniform (s_load pipe).
// Blocks 768..775: intercept partial row-sums into ws_int.
__global__ __launch_bounds__(192) void k_pair_energy(
    const float* __restrict__ p1, const float* __restrict__ p2T,
    const float* __restrict__ W2, const float* __restrict__ b2,
    const float* __restrict__ dmv, const float* __restrict__ charge1,
    const float* __restrict__ charge2, const float* __restrict__ veps,
    const float* __restrict__ vsig, const float* __restrict__ valid1,
    const float* __restrict__ valid2, const float* __restrict__ nm1,
    const float* __restrict__ nm2, const float* __restrict__ vdw_coeff,
    const float* __restrict__ h1g, float* __restrict__ ws_int,
    float* __restrict__ out) {
  int tid = threadIdx.x;
  if (blockIdx.x >= 768) {  // ---- intercept partials: 8 blocks, 96 i-rows each
    int eb = blockIdx.x - 768;
    int b = eb >> 2, ch = eb & 3;
    if (tid < DD) {
      float acc = 0.f;
      int i0 = ch * 96;
#pragma unroll 4
      for (int i = 0; i < 96; ++i) {
        int gi = b * NN + i0 + i;
        acc += h1g[gi * DD + tid] * valid1[gi];
      }
      ws_int[eb * DD + tid] = acc;
    }
    return;
  }
  const int TI = 2;
  int tile = blockIdx.x >> 1, jh = blockIdx.x & 1;
  int r0 = tile * TI;
  int b = r0 / NN;
  int j = jh * 192 + tid;
  int col = b * NN + j;

  const float* q0 = p1 + (r0 + 0) * 5 * HH;   // uniform
  const float* q1 = p1 + (r0 + 1) * 5 * HH;   // uniform
  float acc0[5], acc1[5];
#pragma unroll
  for (int m = 0; m < 5; ++m) {
    const float* p2c = p2T + m * HH * PCOLS + col;
    const float* w2m = W2 + m * HH;
    const float* x0 = q0 + m * HH;
    const float* x1 = q1 + m * HH;
    float a0 = b2[m], a1 = b2[m];
#pragma unroll 8
    for (int h = 0; h < HH; ++h) {
      float pv = p2c[h * PCOLS];
      float w = w2m[h];
      a0 += fmaxf(x0[h] + pv, 0.f) * w;
      a1 += fmaxf(x1[h] + pv, 0.f) * w;
    }
    acc0[m] = a0; acc1[m] = a1;
  }

  float q2c = charge2[col], v2 = valid2[col], n2 = nm2[col];
  float vc2 = vdw_coeff[0] * vdw_coeff[0];
  float ec_sum = 0.f, ev_sum = 0.f;
#pragma unroll
  for (int ti = 0; ti < TI; ++ti) {
    const float* am = ti ? acc1 : acc0;
    int gi = r0 + ti;
    int pidx = gi * NN + j;
    float dx = dmv[pidx * 3 + 0], dy = dmv[pidx * 3 + 1], dz = dmv[pidx * 3 + 2];
    float dm = sqrtf(dx * dx + dy * dy + dz * dz + 1e-10f);
    if (dm < 0.5f) dm = 1e10f;
    // coulomb
    float cA = sigmoidf_(am[0]);
    float cN = sigmoidf_(am[1]) * 2.f + 1.f;
    float e_c = cA * charge1[gi] * q2c * __powf(1.f / dm, cN);
    e_c *= valid1[gi] * v2;
    e_c = fminf(fmaxf(e_c, -100.f), 100.f);
    ec_sum += e_c;
    // vdw
    float vA = (sigmoidf_(am[2]) * 0.6f + 0.7f) * vc2 * veps[pidx];
    float vB = tanhf_(am[3]) * 0.6f + 0.7f;
    float vN = sigmoidf_(am[4]) * 2.f + 5.f;
    float dm0 = vsig[pidx] * vB;
    if (dm0 < 1e-4f) dm0 = 1.f;
    float rr = __powf(dm0 / dm, vN);
    float e_v = vA * (rr * rr - 2.f * rr);
    e_v *= nm1[gi] * n2;
    e_v = fminf(e_v, 100.f);
    ev_sum += e_v;
  }
#pragma unroll
  for (int off = 32; off > 0; off >>= 1) {
    ec_sum += __shfl_down(ec_sum, off);
    ev_sum += __shfl_down(ev_sum, off);
  }
  __shared__ float rec[3], rev[3];
  if ((tid & 63) == 0) { rec[tid >> 6] = ec_sum; rev[tid >> 6] = ev_sum; }
  __syncthreads();
  if (tid == 0) {
    atomicAdd(&out[b * 4 + 0], rec[0] + rec[1] + rec[2]);
    atomicAdd(&out[b * 4 + 1], rev[0] + rev[1] + rev[2]);
  }
}

// ---------------------------------------------------------------- intercept finish
__global__ __launch_bounds__(256) void k_intercept_fin(
    const float* __restrict__ ws_int, const float* __restrict__ W1,
    const float* __restrict__ b1, const float* __restrict__ W2,
    const float* __restrict__ b2, float* __restrict__ out) {
  int b = blockIdx.x;
  int tid = threadIdx.x, c = tid & 127, kh = tid >> 7;
  __shared__ float hsf[DD];
  __shared__ float ph[2][DD];
  __shared__ float redw[2];
  if (tid < DD)
    hsf[tid] = ws_int[(b * 4 + 0) * DD + tid] + ws_int[(b * 4 + 1) * DD + tid]
             + ws_int[(b * 4 + 2) * DD + tid] + ws_int[(b * 4 + 3) * DD + tid];
  __syncthreads();
  float acc = 0.f;
  const float* Wp = W1 + (kh * 64) * HH + c;
#pragma unroll 4
  for (int k = 0; k < 64; ++k) acc += hsf[kh * 64 + k] * Wp[k * HH];
  ph[kh][c] = acc;
  __syncthreads();
  if (tid < DD) {
    float hid = fmaxf(ph[0][tid] + ph[1][tid] + b1[tid], 0.f);
    float v = hid * W2[tid];
#pragma unroll
    for (int off = 32; off > 0; off >>= 1) v += __shfl_down(v, off);
    if ((tid & 63) == 0) redw[tid >> 6] = v;
  }
  __syncthreads();
  if (tid == 0) out[b * 4 + 3] = redw[0] + redw[1] + b2[0];
}

// ---------------------------------------------------------------- launch
extern "C" void kernel_launch(void* const* d_in, const int* in_sizes, int n_in,
                              void* d_out, int out_size, void* d_ws, size_t ws_size,
                              hipStream_t stream) {
  (void)in_sizes; (void)n_in; (void)out_size; (void)ws_size;
  const float* h1         = (const float*)d_in[0];
  const float* h2         = (const float*)d_in[1];
  const float* adj1       = (const float*)d_in[2];
  const float* dmv        = (const float*)d_in[3];
  const float* charge1    = (const float*)d_in[4];
  const float* charge2    = (const float*)d_in[5];
  const float* veps       = (const float*)d_in[6];
  const float* vsig       = (const float*)d_in[7];
  const float* delta_uff  = (const float*)d_in[8];
  const float* valid1     = (const float*)d_in[9];
  const float* valid2     = (const float*)d_in[10];
  const float* nm1        = (const float*)d_in[11];
  const float* nm2        = (const float*)d_in[12];
  const float* node_W     = (const float*)d_in[13];
  const float* gat_W      = (const float*)d_in[14];
  const float* gat_Wb     = (const float*)d_in[15];
  const float* gat_A      = (const float*)d_in[16];
  const float* gat_gW     = (const float*)d_in[17];
  const float* gat_gb     = (const float*)d_in[18];
  const float* pW1        = (const float*)d_in[19];
  const float* pb1        = (const float*)d_in[20];
  const float* pW2        = (const float*)d_in[21];
  const float* pb2        = (const float*)d_in[22];
  const float* vdw_coeff  = (const float*)d_in[23];
  const float* duff_coeff = (const float*)d_in[24];
  const float* iW1        = (const float*)d_in[25];
  const float* ib1        = (const float*)d_in[26];
  const float* iW2        = (const float*)d_in[27];
  const float* ib2        = (const float*)d_in[28];
  float* out = (float*)d_out;

  float* ws = (float*)d_ws;
  const int RN = BB * NN * DD;  // 98304
  float* h1gA   = ws;
  float* h1gB   = h1gA + RN;
  float* h2g    = h1gB + RN;
  float* hbuf   = h2g + RN;
  float* hAbuf  = hbuf + RN;
  float* hTbuf  = hAbuf + RN;
  float* hATbuf = hTbuf + RN;
  float* attT   = hATbuf + RN;              // BB*NN*NN
  float* p1     = attT + BB * NN * NN;      // BB*NN*5*HH
  float* p2T    = p1 + BB * NN * 5 * HH;    // 5*HH*PCOLS (same size)
  float* ws_int = p2T + 5 * HH * PCOLS;     // 8*128

  k_embed<<<dim3(2 * BB * NN / 2), dim3(256), 0, stream>>>(h1, h2, node_W, h1gA, h2g);

  float* cur = h1gA;
  float* nxt = h1gB;
  for (int l = 0; l < 3; ++l) {
    k_gat_hhA<<<dim3(BB * NN), dim3(256), 0, stream>>>(
        cur, gat_W + l * DD * DD, gat_Wb + l * DD, gat_A + l * DD * DD,
        hbuf, hAbuf, hTbuf, hATbuf);
    k_gat_att<<<dim3(BB * NN), dim3(384), 0, stream>>>(
        hbuf, hAbuf, hTbuf, hATbuf, adj1, attT);
    k_gat_out<<<dim3(BB * NN), dim3(256), 0, stream>>>(
        cur, hbuf, attT, gat_gW + l * 2 * DD, gat_gb + l, nxt);
    float* t = cur; cur = nxt; nxt = t;
  }
  const float* h1gF = cur;

  k_pair_proj<<<dim3((2 * BB * NN / 16) * 5), dim3(256), 0, stream>>>(
      h1gF, h2g, pW1, pb1, delta_uff, duff_coeff, p1, p2T, out);
  k_pair_energy<<<dim3(768 + 8), dim3(192), 0, stream>>>(
      p1, p2T, pW2, pb2, dmv, charge1, charge2, veps, vsig,
      valid1, valid2, nm1, nm2, vdw_coeff, h1gF, ws_int, out);
  k_intercept_fin<<<dim3(BB), dim3(256), 0, stream>>>(ws_int, iW1, ib1, iW2, ib2, out);
}

// Round 5
// 316.238 us; speedup vs baseline: 1.3272x; 1.0300x over previous
//
#include <hip/hip_runtime.h>
#include <math.h>

#define BB 2
#define NN 384   // N1 == N2
#define DD 128   // D
#define HH 128   // H
#define RT_ALL (BB * NN)        // 768 rows per side
#define PCOLS (BB * NN)         // 768: width of transposed/packed layouts

__device__ __forceinline__ float sigmoidf_(float x) { return 1.f / (1.f + __expf(-x)); }
__device__ __forceinline__ float tanhf_(float x)    { return 1.f - 2.f / (__expf(2.f * x) + 1.f); }

// ---------------------------------------------------------------- embed
__global__ __launch_bounds__(256) void k_embed(
    const float* __restrict__ h1, const float* __restrict__ h2,
    const float* __restrict__ nW, float* __restrict__ h1g, float* __restrict__ h2g) {
  int r0 = blockIdx.x * 2;
  int tid = threadIdx.x;
  const float* src; float* dst; int rb;
  if (r0 < RT_ALL) { src = h1; dst = h1g; rb = r0; }
  else             { src = h2; dst = h2g; rb = r0 - RT_ALL; }
  __shared__ float xs[2][54];
  if (tid < 108) xs[tid / 54][tid % 54] = src[rb * 54 + tid];
  __syncthreads();
  int rr = tid >> 7, c = tid & 127;
  float acc = 0.f;
#pragma unroll 6
  for (int k = 0; k < 54; ++k) acc += xs[rr][k] * nW[k * DD + c];
  dst[(rb + rr) * DD + c] = acc;
}

// ---------------------------------------------------------------- GAT h & hA
// 1 row per block, k-split 2 across 256 thr. Writes row-major h/hA and
// transposed hT/hAT ([c][row], width 768) for the attention kernel.
__global__ __launch_bounds__(256) void k_gat_hhA(
    const float* __restrict__ x, const float* __restrict__ W,
    const float* __restrict__ Wb, const float* __restrict__ A,
    float* __restrict__ h, float* __restrict__ hA,
    float* __restrict__ hT, float* __restrict__ hAT) {
  int r = blockIdx.x;
  int tid = threadIdx.x, c = tid & 127, kh = tid >> 7;
  __shared__ float xs[DD], hs[DD];
  __shared__ float ph[2][DD];
  if (tid < DD) xs[tid] = x[r * DD + tid];
  __syncthreads();
  float acc = 0.f;
  const float* Wp = W + (kh * 64) * DD + c;
#pragma unroll 4
  for (int k = 0; k < 64; ++k) acc += xs[kh * 64 + k] * Wp[k * DD];
  ph[kh][c] = acc;
  __syncthreads();
  if (tid < DD) {
    float hv = ph[0][tid] + ph[1][tid] + Wb[tid];
    h[r * DD + tid] = hv; hT[tid * PCOLS + r] = hv; hs[tid] = hv;
  }
  __syncthreads();
  acc = 0.f;
  const float* Ap = A + (kh * 64) * DD + c;
#pragma unroll 4
  for (int k = 0; k < 64; ++k) acc += hs[kh * 64 + k] * Ap[k * DD];
  ph[kh][c] = acc;
  __syncthreads();
  if (tid < DD) {
    float av = ph[0][tid] + ph[1][tid];
    hA[r * DD + tid] = av; hAT[tid * PCOLS + r] = av;
  }
}

// ---------------------------------------------------------------- GAT attention
// One softmax column k per block -> 768 blocks, 384 thr (lane = j).
// hT/hAT coalesced over j; the k-row of h/hA staged in LDS (broadcast).
// Stores att ROW-MAJOR att[b][j][k] (divergent stores — fire-and-forget, cheap)
// so k_gat_out can read its row coalesced.
__global__ __launch_bounds__(384) void k_gat_att(
    const float* __restrict__ h, const float* __restrict__ hA,
    const float* __restrict__ hT, const float* __restrict__ hAT,
    const float* __restrict__ adj, float* __restrict__ att) {
  int col = blockIdx.x;          // b*NN + k
  int b = col / NN, k = col - b * NN;
  int tid = threadIdx.x;         // j
  __shared__ float hrow_s[DD], hArow_s[DD];
  __shared__ float rmx[6], rsm[6];
  if (tid < DD) hrow_s[tid] = h[col * DD + tid];
  else if (tid < 2 * DD) hArow_s[tid - DD] = hA[col * DD + tid - DD];
  __syncthreads();
  const float* hTb  = hT  + b * NN + tid;
  const float* hATb = hAT + b * NN + tid;
  float e = 0.f;
#pragma unroll 8
  for (int c = 0; c < DD; ++c)
    e += hATb[c * PCOLS] * hrow_s[c] + hTb[c * PCOLS] * hArow_s[c];
  float a = adj[col * NN + tid];  // == adj[(b*NN+j)*NN+k] by symmetry
  float lmax = (a > 0.f) ? e : -3e38f;
#pragma unroll
  for (int off = 32; off > 0; off >>= 1) lmax = fmaxf(lmax, __shfl_down(lmax, off));
  if ((tid & 63) == 0) rmx[tid >> 6] = lmax;
  __syncthreads();
  float m = fmaxf(fmaxf(fmaxf(rmx[0], rmx[1]), fmaxf(rmx[2], rmx[3])), fmaxf(rmx[4], rmx[5]));
  float v = (a > 0.f) ? __expf(e - m) : 0.f;
  float s = v;
#pragma unroll
  for (int off = 32; off > 0; off >>= 1) s += __shfl_down(s, off);
  if ((tid & 63) == 0) rsm[tid >> 6] = s;
  __syncthreads();
  float inv = 1.f / (rsm[0] + rsm[1] + rsm[2] + rsm[3] + rsm[4] + rsm[5]);
  att[(b * NN + tid) * NN + k] = v * a * inv;   // row-major, divergent store
}

// ---------------------------------------------------------------- GAT output + gate
// 1 row i per block, j-split 2 across 256 thr. att row read coalesced (float4).
__global__ __launch_bounds__(256) void k_gat_out(
    const float* __restrict__ x, const float* __restrict__ h,
    const float* __restrict__ att, const float* __restrict__ gW,
    const float* __restrict__ gb, float* __restrict__ out) {
  int r = blockIdx.x;            // b*NN + i
  int b = r / NN;
  int tid = threadIdx.x, c = tid & 127, jh = tid >> 7;
  __shared__ float arow[NN];
  __shared__ float ph[2][DD];
  __shared__ float redw[2];
  if (tid < 96) ((float4*)arow)[tid] = ((const float4*)(att + r * NN))[tid];
  __syncthreads();
  float accA = 0.f, accB = 0.f;
  const float* hp = h + (b * NN + jh * 192) * DD + c;
  const float* ar = arow + jh * 192;
#pragma unroll 4
  for (int jj = 0; jj < 192; jj += 2) {
    accA += ar[jj] * hp[jj * DD];
    accB += ar[jj + 1] * hp[(jj + 1) * DD];
  }
  ph[jh][c] = accA + accB;
  __syncthreads();
  if (tid < DD) {
    float hpr = fmaxf(ph[0][tid] + ph[1][tid], 0.f);
    float xr = x[r * DD + tid];
    float v = xr * gW[tid] + hpr * gW[DD + tid];
#pragma unroll
    for (int off = 32; off > 0; off >>= 1) v += __shfl_down(v, off);
    if ((tid & 63) == 0) redw[tid >> 6] = v;
  }
  __syncthreads();
  if (tid < DD) {
    float hpr = fmaxf(ph[0][tid] + ph[1][tid], 0.f);
    float xr = x[r * DD + tid];
    float coeff = sigmoidf_(redw[0] + redw[1] + gb[0]);
    out[r * DD + tid] = coeff * xr + (1.f - coeff) * hpr;
  }
}

// ---------------------------------------------------------------- pair projections
// 16 rows × 1 m per block, k-split 2 -> 480 blocks. Ligand -> p1 row-major
// (bias folded). Protein -> p2q PACKED float4: [m][h/4][col][4].
__global__ __launch_bounds__(256) void k_pair_proj(
    const float* __restrict__ h1g, const float* __restrict__ h2g,
    const float* __restrict__ W1, const float* __restrict__ b1,
    const float* __restrict__ delta_uff, const float* __restrict__ duff_coeff,
    float* __restrict__ p1, float* __restrict__ p2q, float* __restrict__ out) {
  const int RT = 16;
  int m = blockIdx.x % 5;
  int r0 = (blockIdx.x / 5) * RT;
  int tid = threadIdx.x, c = tid & 127, kh = tid >> 7;
  if (blockIdx.x == 0 && tid < BB * 4) {
    int bb = tid >> 2, cc = tid & 3;
    out[tid] = (cc == 2) ? duff_coeff[0] * duff_coeff[0] * delta_uff[bb] : 0.f;
  }
  bool lig = (r0 < RT_ALL);
  const float* src = lig ? h1g : h2g;
  int rb = lig ? r0 : r0 - RT_ALL;
  const float* W = W1 + (m * 256 + (lig ? 0 : 128)) * HH;
  __shared__ float xs[RT][DD];
  __shared__ float ps[RT][DD];
  for (int idx = tid; idx < RT * DD; idx += 256) xs[idx >> 7][idx & 127] = src[rb * DD + idx];
  __syncthreads();
  float acc[RT];
#pragma unroll
  for (int r = 0; r < RT; ++r) acc[r] = 0.f;
  const float* Wp = W + (kh * 64) * HH + c;
#pragma unroll 2
  for (int k = 0; k < 64; ++k) {
    float w = Wp[k * HH];
#pragma unroll
    for (int r = 0; r < RT; ++r) acc[r] += xs[r][kh * 64 + k] * w;
  }
  if (kh == 1) {
#pragma unroll
    for (int r = 0; r < RT; ++r) ps[r][c] = acc[r];
  }
  __syncthreads();
  if (kh == 0) {
    if (lig) {
      float bias = b1[m * HH + c];
#pragma unroll
      for (int r = 0; r < RT; ++r)
        p1[((rb + r) * 5 + m) * HH + c] = acc[r] + ps[r][c] + bias;
    } else {
      // packed dword offset: (g*PCOLS + col)*4 + (c&3), g = m*32 + c/4
      int g = m * (HH / 4) + (c >> 2);
      float* dst = p2q + (size_t)(g * PCOLS + rb) * 4 + (c & 3);
#pragma unroll
      for (int r = 0; r < RT; ++r) dst[4 * r] = acc[r] + ps[r][c];
    }
  }
}

// ---------------------------------------------------------------- pair energies
// Blocks 0..767: TI=2 ligand rows × 192-j half, 192 thr, lane = j.
// p2q float4 loads coalesced over lanes (160/lane); p1 tiles + W2 in LDS
// (broadcast reads). Blocks 768..775: intercept partial row-sums.
__global__ __launch_bounds__(192) void k_pair_energy(
    const float* __restrict__ p1, const float* __restrict__ p2q,
    const float* __restrict__ W2, const float* __restrict__ b2,
    const float* __restrict__ dmv, const float* __restrict__ charge1,
    const float* __restrict__ charge2, const float* __restrict__ veps,
    const float* __restrict__ vsig, const float* __restrict__ valid1,
    const float* __restrict__ valid2, const float* __restrict__ nm1,
    const float* __restrict__ nm2, const float* __restrict__ vdw_coeff,
    const float* __restrict__ h1g, float* __restrict__ ws_int,
    float* __restrict__ out) {
  int tid = threadIdx.x;
  if (blockIdx.x >= 768) {  // ---- intercept partials: 8 blocks, 96 i-rows each
    int eb = blockIdx.x - 768;
    int b = eb >> 2, ch = eb & 3;
    if (tid < DD) {
      float acc = 0.f;
      int i0 = ch * 96;
#pragma unroll 4
      for (int i = 0; i < 96; ++i) {
        int gi = b * NN + i0 + i;
        acc += h1g[gi * DD + tid] * valid1[gi];
      }
      ws_int[eb * DD + tid] = acc;
    }
    return;
  }
  const int TI = 2;
  int tile = blockIdx.x >> 1, jh = blockIdx.x & 1;
  int r0 = tile * TI;
  int b = r0 / NN;
  int j = jh * 192 + tid;
  int col = b * NN + j;

  __shared__ float4 p1s4[2][5 * HH / 4];   // 2 rows × 160 float4
  __shared__ float4 w2s4[5 * HH / 4];
  {
    const float4* p1g = (const float4*)(p1 + r0 * 5 * HH);
    for (int idx = tid; idx < 2 * 160; idx += 192) p1s4[idx / 160][idx % 160] = p1g[idx];
    if (tid < 160) w2s4[tid] = ((const float4*)W2)[tid];
  }
  __syncthreads();

  const float4* p2q4 = (const float4*)p2q;
  float acc0[5], acc1[5];
#pragma unroll
  for (int m = 0; m < 5; ++m) {
    const float4* pc = p2q4 + (size_t)(m * 32) * PCOLS + col;
    float a0 = 0.f, a1 = 0.f;
#pragma unroll 8
    for (int hq = 0; hq < 32; ++hq) {
      float4 pv = pc[(size_t)hq * PCOLS];
      float4 x0 = p1s4[0][m * 32 + hq];
      float4 x1 = p1s4[1][m * 32 + hq];
      float4 w  = w2s4[m * 32 + hq];
      a0 += fmaxf(x0.x + pv.x, 0.f) * w.x + fmaxf(x0.y + pv.y, 0.f) * w.y
          + fmaxf(x0.z + pv.z, 0.f) * w.z + fmaxf(x0.w + pv.w, 0.f) * w.w;
      a1 += fmaxf(x1.x + pv.x, 0.f) * w.x + fmaxf(x1.y + pv.y, 0.f) * w.y
          + fmaxf(x1.z + pv.z, 0.f) * w.z + fmaxf(x1.w + pv.w, 0.f) * w.w;
    }
    acc0[m] = a0 + b2[m]; acc1[m] = a1 + b2[m];
  }

  float q2c = charge2[col], v2 = valid2[col], n2 = nm2[col];
  float vc2 = vdw_coeff[0] * vdw_coeff[0];
  float ec_sum = 0.f, ev_sum = 0.f;
#pragma unroll
  for (int ti = 0; ti < TI; ++ti) {
    const float* am = ti ? acc1 : acc0;
    int gi = r0 + ti;
    int pidx = gi * NN + j;
    float dx = dmv[pidx * 3 + 0], dy = dmv[pidx * 3 + 1], dz = dmv[pidx * 3 + 2];
    float dm = sqrtf(dx * dx + dy * dy + dz * dz + 1e-10f);
    if (dm < 0.5f) dm = 1e10f;
    // coulomb
    float cA = sigmoidf_(am[0]);
    float cN = sigmoidf_(am[1]) * 2.f + 1.f;
    float e_c = cA * charge1[gi] * q2c * __powf(1.f / dm, cN);
    e_c *= valid1[gi] * v2;
    e_c = fminf(fmaxf(e_c, -100.f), 100.f);
    ec_sum += e_c;
    // vdw
    float vA = (sigmoidf_(am[2]) * 0.6f + 0.7f) * vc2 * veps[pidx];
    float vB = tanhf_(am[3]) * 0.6f + 0.7f;
    float vN = sigmoidf_(am[4]) * 2.f + 5.f;
    float dm0 = vsig[pidx] * vB;
    if (dm0 < 1e-4f) dm0 = 1.f;
    float rr = __powf(dm0 / dm, vN);
    float e_v = vA * (rr * rr - 2.f * rr);
    e_v *= nm1[gi] * n2;
    e_v = fminf(e_v, 100.f);
    ev_sum += e_v;
  }
#pragma unroll
  for (int off = 32; off > 0; off >>= 1) {
    ec_sum += __shfl_down(ec_sum, off);
    ev_sum += __shfl_down(ev_sum, off);
  }
  __shared__ float rec[3], rev[3];
  if ((tid & 63) == 0) { rec[tid >> 6] = ec_sum; rev[tid >> 6] = ev_sum; }
  __syncthreads();
  if (tid == 0) {
    atomicAdd(&out[b * 4 + 0], rec[0] + rec[1] + rec[2]);
    atomicAdd(&out[b * 4 + 1], rev[0] + rev[1] + rev[2]);
  }
}

// ---------------------------------------------------------------- intercept finish
__global__ __launch_bounds__(256) void k_intercept_fin(
    const float* __restrict__ ws_int, const float* __restrict__ W1,
    const float* __restrict__ b1, const float* __restrict__ W2,
    const float* __restrict__ b2, float* __restrict__ out) {
  int b = blockIdx.x;
  int tid = threadIdx.x, c = tid & 127, kh = tid >> 7;
  __shared__ float hsf[DD];
  __shared__ float ph[2][DD];
  __shared__ float redw[2];
  if (tid < DD)
    hsf[tid] = ws_int[(b * 4 + 0) * DD + tid] + ws_int[(b * 4 + 1) * DD + tid]
             + ws_int[(b * 4 + 2) * DD + tid] + ws_int[(b * 4 + 3) * DD + tid];
  __syncthreads();
  float acc = 0.f;
  const float* Wp = W1 + (kh * 64) * HH + c;
#pragma unroll 4
  for (int k = 0; k < 64; ++k) acc += hsf[kh * 64 + k] * Wp[k * HH];
  ph[kh][c] = acc;
  __syncthreads();
  if (tid < DD) {
    float hid = fmaxf(ph[0][tid] + ph[1][tid] + b1[tid], 0.f);
    float v = hid * W2[tid];
#pragma unroll
    for (int off = 32; off > 0; off >>= 1) v += __shfl_down(v, off);
    if ((tid & 63) == 0) redw[tid >> 6] = v;
  }
  __syncthreads();
  if (tid == 0) out[b * 4 + 3] = redw[0] + redw[1] + b2[0];
}

// ---------------------------------------------------------------- launch
extern "C" void kernel_launch(void* const* d_in, const int* in_sizes, int n_in,
                              void* d_out, int out_size, void* d_ws, size_t ws_size,
                              hipStream_t stream) {
  (void)in_sizes; (void)n_in; (void)out_size; (void)ws_size;
  const float* h1         = (const float*)d_in[0];
  const float* h2         = (const float*)d_in[1];
  const float* adj1       = (const float*)d_in[2];
  const float* dmv        = (const float*)d_in[3];
  const float* charge1    = (const float*)d_in[4];
  const float* charge2    = (const float*)d_in[5];
  const float* veps       = (const float*)d_in[6];
  const float* vsig       = (const float*)d_in[7];
  const float* delta_uff  = (const float*)d_in[8];
  const float* valid1     = (const float*)d_in[9];
  const float* valid2     = (const float*)d_in[10];
  const float* nm1        = (const float*)d_in[11];
  const float* nm2        = (const float*)d_in[12];
  const float* node_W     = (const float*)d_in[13];
  const float* gat_W      = (const float*)d_in[14];
  const float* gat_Wb     = (const float*)d_in[15];
  const float* gat_A      = (const float*)d_in[16];
  const float* gat_gW     = (const float*)d_in[17];
  const float* gat_gb     = (const float*)d_in[18];
  const float* pW1        = (const float*)d_in[19];
  const float* pb1        = (const float*)d_in[20];
  const float* pW2        = (const float*)d_in[21];
  const float* pb2        = (const float*)d_in[22];
  const float* vdw_coeff  = (const float*)d_in[23];
  const float* duff_coeff = (const float*)d_in[24];
  const float* iW1        = (const float*)d_in[25];
  const float* ib1        = (const float*)d_in[26];
  const float* iW2        = (const float*)d_in[27];
  const float* ib2        = (const float*)d_in[28];
  float* out = (float*)d_out;

  float* ws = (float*)d_ws;
  const int RN = BB * NN * DD;  // 98304
  float* h1gA   = ws;
  float* h1gB   = h1gA + RN;
  float* h2g    = h1gB + RN;
  float* hbuf   = h2g + RN;
  float* hAbuf  = hbuf + RN;
  float* hTbuf  = hAbuf + RN;
  float* hATbuf = hTbuf + RN;
  float* att    = hATbuf + RN;              // BB*NN*NN row-major
  float* p1     = att + BB * NN * NN;       // BB*NN*5*HH
  float* p2q    = p1 + BB * NN * 5 * HH;    // 5*(HH/4)*PCOLS float4 (same size)
  float* ws_int = p2q + 5 * HH * PCOLS;     // 8*128

  k_embed<<<dim3(2 * BB * NN / 2), dim3(256), 0, stream>>>(h1, h2, node_W, h1gA, h2g);

  float* cur = h1gA;
  float* nxt = h1gB;
  for (int l = 0; l < 3; ++l) {
    k_gat_hhA<<<dim3(BB * NN), dim3(256), 0, stream>>>(
        cur, gat_W + l * DD * DD, gat_Wb + l * DD, gat_A + l * DD * DD,
        hbuf, hAbuf, hTbuf, hATbuf);
    k_gat_att<<<dim3(BB * NN), dim3(384), 0, stream>>>(
        hbuf, hAbuf, hTbuf, hATbuf, adj1, att);
    k_gat_out<<<dim3(BB * NN), dim3(256), 0, stream>>>(
        cur, hbuf, att, gat_gW + l * 2 * DD, gat_gb + l, nxt);
    float* t = cur; cur = nxt; nxt = t;
  }
  const float* h1gF = cur;

  k_pair_proj<<<dim3((2 * BB * NN / 16) * 5), dim3(256), 0, stream>>>(
      h1gF, h2g, pW1, pb1, delta_uff, duff_coeff, p1, p2q, out);
  k_pair_energy<<<dim3(768 + 8), dim3(192), 0, stream>>>(
      p1, p2q, pW2, pb2, dmv, charge1, charge2, veps, vsig,
      valid1, valid2, nm1, nm2, vdw_coeff, h1gF, ws_int, out);
  k_intercept_fin<<<dim3(BB), dim3(256), 0, stream>>>(ws_int, iW1, ib1, iW2, ib2, out);
}

// Round 6
// 302.110 us; speedup vs baseline: 1.3892x; 1.0468x over previous
//
#include <hip/hip_runtime.h>
#include <math.h>

#define BB 2
#define NN 384   // N1 == N2
#define DD 128   // D
#define HH 128   // H
#define RT_ALL (BB * NN)        // 768 rows per side
#define PCOLS (BB * NN)         // 768: width of transposed/packed layouts

__device__ __forceinline__ float sigmoidf_(float x) { return 1.f / (1.f + __expf(-x)); }
__device__ __forceinline__ float tanhf_(float x)    { return 1.f - 2.f / (__expf(2.f * x) + 1.f); }

// ---------------------------------------------------------------- embed
__global__ __launch_bounds__(256) void k_embed(
    const float* __restrict__ h1, const float* __restrict__ h2,
    const float* __restrict__ nW, float* __restrict__ h1g, float* __restrict__ h2g) {
  int r0 = blockIdx.x * 2;
  int tid = threadIdx.x;
  const float* src; float* dst; int rb;
  if (r0 < RT_ALL) { src = h1; dst = h1g; rb = r0; }
  else             { src = h2; dst = h2g; rb = r0 - RT_ALL; }
  int rr = tid >> 7, c = tid & 127;
  // x row read uniform-per-wave (rr) -> broadcast; weights coalesced over c
  const float* xr = src + (rb + rr) * 54;
  float acc = 0.f;
#pragma unroll 6
  for (int k = 0; k < 54; ++k) acc += xr[k] * nW[k * DD + c];
  dst[(rb + rr) * DD + c] = acc;
}

// ---------------------------------------------------------------- GAT h & hA
// 2 rows per block (shared W/A streams), k-split 2 across 256 thr -> 384 blocks.
// x rows read via uniform index (scalar-broadcast), W/A coalesced over c.
__global__ __launch_bounds__(256) void k_gat_hhA(
    const float* __restrict__ x, const float* __restrict__ W,
    const float* __restrict__ Wb, const float* __restrict__ A,
    float* __restrict__ h, float* __restrict__ hA,
    float* __restrict__ hT, float* __restrict__ hAT) {
  int r0 = blockIdx.x * 2;
  int tid = threadIdx.x, c = tid & 127, kh = tid >> 7;
  __shared__ float ph[2][2][DD];   // [kh][row][c]
  __shared__ float hs[2][DD];
  const float* x0 = x + (r0 + 0) * DD + kh * 64;
  const float* x1 = x + (r0 + 1) * DD + kh * 64;
  const float* Wp = W + (kh * 64) * DD + c;
  float a00 = 0.f, a01 = 0.f, a10 = 0.f, a11 = 0.f;  // [row][k-parity]
#pragma unroll 4
  for (int k = 0; k < 64; k += 2) {
    float w0 = Wp[k * DD], w1 = Wp[(k + 1) * DD];
    a00 += x0[k] * w0; a01 += x0[k + 1] * w1;
    a10 += x1[k] * w0; a11 += x1[k + 1] * w1;
  }
  ph[kh][0][c] = a00 + a01;
  ph[kh][1][c] = a10 + a11;
  __syncthreads();
  {  // thread (c, kh) finalizes row kh
    float hv = ph[0][kh][c] + ph[1][kh][c] + Wb[c];
    h[(r0 + kh) * DD + c] = hv;
    hT[c * PCOLS + r0 + kh] = hv;
    hs[kh][c] = hv;
  }
  __syncthreads();
  const float* Ap = A + (kh * 64) * DD + c;
  a00 = a01 = a10 = a11 = 0.f;
#pragma unroll 4
  for (int k = 0; k < 64; k += 2) {
    float w0 = Ap[k * DD], w1 = Ap[(k + 1) * DD];
    a00 += hs[0][kh * 64 + k] * w0; a01 += hs[0][kh * 64 + k + 1] * w1;
    a10 += hs[1][kh * 64 + k] * w0; a11 += hs[1][kh * 64 + k + 1] * w1;
  }
  __syncthreads();
  ph[kh][0][c] = a00 + a01;
  ph[kh][1][c] = a10 + a11;
  __syncthreads();
  {
    float av = ph[0][kh][c] + ph[1][kh][c];
    hA[(r0 + kh) * DD + c] = av;
    hAT[c * PCOLS + r0 + kh] = av;
  }
}

// ---------------------------------------------------------------- GAT attention
// KT=2 softmax columns per block -> 384 blocks, 384 thr (lane = j).
// hT/hAT coalesced over j and SHARED between the two columns; the k-rows of
// h/hA are uniform global reads (scalar pipe). Stores att row-major as float2.
__global__ __launch_bounds__(384) void k_gat_att(
    const float* __restrict__ h, const float* __restrict__ hA,
    const float* __restrict__ hT, const float* __restrict__ hAT,
    const float* __restrict__ adj, float* __restrict__ att) {
  int b = blockIdx.x / (NN / 2);
  int k0 = (blockIdx.x % (NN / 2)) * 2;
  int col0 = b * NN + k0, col1 = col0 + 1;
  int tid = threadIdx.x;         // j
  const float* hr0  = h  + col0 * DD;   // uniform
  const float* har0 = hA + col0 * DD;
  const float* hr1  = h  + col1 * DD;
  const float* har1 = hA + col1 * DD;
  const float* hTb  = hT  + b * NN + tid;
  const float* hATb = hAT + b * NN + tid;
  float e0a = 0.f, e0b = 0.f, e1a = 0.f, e1b = 0.f;
#pragma unroll 4
  for (int c = 0; c < DD; ++c) {
    float hTv = hTb[c * PCOLS], hATv = hATb[c * PCOLS];
    e0a += hATv * hr0[c]; e0b += hTv * har0[c];
    e1a += hATv * hr1[c]; e1b += hTv * har1[c];
  }
  float e0 = e0a + e0b, e1 = e1a + e1b;
  float a0 = adj[col0 * NN + tid];  // == adj[j][k0] by symmetry, coalesced
  float a1 = adj[col1 * NN + tid];
  __shared__ float rmx0[6], rmx1[6], rsm0[6], rsm1[6];
  float l0 = (a0 > 0.f) ? e0 : -3e38f;
  float l1 = (a1 > 0.f) ? e1 : -3e38f;
#pragma unroll
  for (int off = 32; off > 0; off >>= 1) {
    l0 = fmaxf(l0, __shfl_down(l0, off));
    l1 = fmaxf(l1, __shfl_down(l1, off));
  }
  if ((tid & 63) == 0) { rmx0[tid >> 6] = l0; rmx1[tid >> 6] = l1; }
  __syncthreads();
  float m0 = rmx0[0], m1 = rmx1[0];
#pragma unroll
  for (int w = 1; w < 6; ++w) { m0 = fmaxf(m0, rmx0[w]); m1 = fmaxf(m1, rmx1[w]); }
  float v0 = (a0 > 0.f) ? __expf(e0 - m0) : 0.f;
  float v1 = (a1 > 0.f) ? __expf(e1 - m1) : 0.f;
  float s0 = v0, s1 = v1;
#pragma unroll
  for (int off = 32; off > 0; off >>= 1) {
    s0 += __shfl_down(s0, off);
    s1 += __shfl_down(s1, off);
  }
  if ((tid & 63) == 0) { rsm0[tid >> 6] = s0; rsm1[tid >> 6] = s1; }
  __syncthreads();
  float d0 = 0.f, d1 = 0.f;
#pragma unroll
  for (int w = 0; w < 6; ++w) { d0 += rsm0[w]; d1 += rsm1[w]; }
  float2 wv = make_float2(v0 * a0 / d0, v1 * a1 / d1);
  *(float2*)(att + (b * NN + tid) * NN + k0) = wv;   // row-major, 8B store
}

// ---------------------------------------------------------------- GAT output + gate
// IT=2 rows per block (shared h stream), j-split 2 across 256 thr -> 384 blocks.
// att rows read via uniform index (broadcast), h coalesced over c.
__global__ __launch_bounds__(256) void k_gat_out(
    const float* __restrict__ x, const float* __restrict__ h,
    const float* __restrict__ att, const float* __restrict__ gW,
    const float* __restrict__ gb, float* __restrict__ out) {
  int r0 = blockIdx.x * 2;       // rows r0, r0+1
  int b = r0 / NN;
  int tid = threadIdx.x, c = tid & 127, jh = tid >> 7;
  __shared__ float ph[2][2][DD];  // [jh][row][c]
  __shared__ float redw[2][2];    // [row][wavepair]
  const float* ar0 = att + (r0 + 0) * NN + jh * 192;  // uniform-per-wave
  const float* ar1 = att + (r0 + 1) * NN + jh * 192;
  const float* hp = h + (b * NN + jh * 192) * DD + c;
  float a0A = 0.f, a0B = 0.f, a1A = 0.f, a1B = 0.f;
#pragma unroll 4
  for (int jj = 0; jj < 192; jj += 2) {
    float hv0 = hp[jj * DD], hv1 = hp[(jj + 1) * DD];
    a0A += ar0[jj] * hv0; a0B += ar0[jj + 1] * hv1;
    a1A += ar1[jj] * hv0; a1B += ar1[jj + 1] * hv1;
  }
  ph[jh][0][c] = a0A + a0B;
  ph[jh][1][c] = a1A + a1B;
  __syncthreads();
  // thread (c, jh) finalizes row jh
  float hpr = fmaxf(ph[0][jh][c] + ph[1][jh][c], 0.f);
  float xr = x[(r0 + jh) * DD + c];
  float v = xr * gW[c] + hpr * gW[DD + c];
#pragma unroll
  for (int off = 32; off > 0; off >>= 1) v += __shfl_down(v, off);
  if ((tid & 63) == 0) redw[jh][(tid >> 6) & 1] = v;
  __syncthreads();
  float coeff = sigmoidf_(redw[jh][0] + redw[jh][1] + gb[0]);
  out[(r0 + jh) * DD + c] = coeff * xr + (1.f - coeff) * hpr;
}

// ---------------------------------------------------------------- pair projections
// 16 rows × 1 m per block, k-split 2 -> 480 blocks. Ligand -> p1 row-major
// (bias folded). Protein -> p2q PACKED float4: [m][h/4][col][4].
__global__ __launch_bounds__(256) void k_pair_proj(
    const float* __restrict__ h1g, const float* __restrict__ h2g,
    const float* __restrict__ W1, const float* __restrict__ b1,
    const float* __restrict__ delta_uff, const float* __restrict__ duff_coeff,
    float* __restrict__ p1, float* __restrict__ p2q, float* __restrict__ out) {
  const int RT = 16;
  int m = blockIdx.x % 5;
  int r0 = (blockIdx.x / 5) * RT;
  int tid = threadIdx.x, c = tid & 127, kh = tid >> 7;
  if (blockIdx.x == 0 && tid < BB * 4) {
    int bb = tid >> 2, cc = tid & 3;
    out[tid] = (cc == 2) ? duff_coeff[0] * duff_coeff[0] * delta_uff[bb] : 0.f;
  }
  bool lig = (r0 < RT_ALL);
  const float* src = lig ? h1g : h2g;
  int rb = lig ? r0 : r0 - RT_ALL;
  const float* W = W1 + (m * 256 + (lig ? 0 : 128)) * HH;
  float acc[RT];
#pragma unroll
  for (int r = 0; r < RT; ++r) acc[r] = 0.f;
  const float* Wp = W + (kh * 64) * HH + c;
  const float* xp = src + rb * DD + kh * 64;  // uniform rows
#pragma unroll 2
  for (int k = 0; k < 64; ++k) {
    float w = Wp[k * HH];
#pragma unroll
    for (int r = 0; r < RT; ++r) acc[r] += xp[r * DD + k] * w;
  }
  __shared__ float ps[RT][DD];
  if (kh == 1) {
#pragma unroll
    for (int r = 0; r < RT; ++r) ps[r][c] = acc[r];
  }
  __syncthreads();
  if (kh == 0) {
    if (lig) {
      float bias = b1[m * HH + c];
#pragma unroll
      for (int r = 0; r < RT; ++r)
        p1[((rb + r) * 5 + m) * HH + c] = acc[r] + ps[r][c] + bias;
    } else {
      // packed dword offset: (g*PCOLS + col)*4 + (c&3), g = m*32 + c/4
      int g = m * (HH / 4) + (c >> 2);
      float* dst = p2q + (size_t)(g * PCOLS + rb) * 4 + (c & 3);
#pragma unroll
      for (int r = 0; r < RT; ++r) dst[4 * r] = acc[r] + ps[r][c];
    }
  }
}

// ---------------------------------------------------------------- pair energies
// Blocks 0..383: TI=2 ligand rows, 384 thr (lane = j, full range).
// p2q float4 coalesced (160 loads/lane); p1/W2/b2 via truly-uniform indices
// -> scalar s_load broadcast (NO LDS in the hot loop).
// Blocks 384..391: intercept partial row-sums.
__global__ __launch_bounds__(384) void k_pair_energy(
    const float* __restrict__ p1, const float* __restrict__ p2q,
    const float* __restrict__ W2, const float* __restrict__ b2,
    const float* __restrict__ dmv, const float* __restrict__ charge1,
    const float* __restrict__ charge2, const float* __restrict__ veps,
    const float* __restrict__ vsig, const float* __restrict__ valid1,
    const float* __restrict__ valid2, const float* __restrict__ nm1,
    const float* __restrict__ nm2, const float* __restrict__ vdw_coeff,
    const float* __restrict__ h1g, float* __restrict__ ws_int,
    float* __restrict__ out) {
  int tid = threadIdx.x;
  if (blockIdx.x >= 384) {  // ---- intercept partials: 8 blocks, 96 i-rows each
    int eb = blockIdx.x - 384;
    int b = eb >> 2, ch = eb & 3;
    if (tid < DD) {
      float acc = 0.f;
      int i0 = ch * 96;
#pragma unroll 4
      for (int i = 0; i < 96; ++i) {
        int gi = b * NN + i0 + i;
        acc += h1g[gi * DD + tid] * valid1[gi];
      }
      ws_int[eb * DD + tid] = acc;
    }
    return;
  }
  int r0 = blockIdx.x * 2;       // ligand rows r0, r0+1
  int b = r0 / NN;
  int j = tid;                   // 0..383
  int col = b * NN + j;

  const float* q0 = p1 + (r0 + 0) * 5 * HH;   // uniform
  const float* q1 = p1 + (r0 + 1) * 5 * HH;   // uniform
  const float4* p2q4 = (const float4*)p2q;
  float acc0[5], acc1[5];
#pragma unroll
  for (int m = 0; m < 5; ++m) {
    const float4* pc = p2q4 + (size_t)(m * 32) * PCOLS + col;
    const float* x0m = q0 + m * HH;
    const float* x1m = q1 + m * HH;
    const float* w2m = W2 + m * HH;
    float a0 = 0.f, a1 = 0.f;
#pragma unroll 8
    for (int hq = 0; hq < 32; ++hq) {
      float4 pv = pc[(size_t)hq * PCOLS];
      float w0 = w2m[4 * hq + 0], w1 = w2m[4 * hq + 1];
      float w2v = w2m[4 * hq + 2], w3 = w2m[4 * hq + 3];
      float x00 = x0m[4 * hq + 0], x01 = x0m[4 * hq + 1];
      float x02 = x0m[4 * hq + 2], x03 = x0m[4 * hq + 3];
      float x10 = x1m[4 * hq + 0], x11 = x1m[4 * hq + 1];
      float x12 = x1m[4 * hq + 2], x13 = x1m[4 * hq + 3];
      a0 += fmaxf(x00 + pv.x, 0.f) * w0 + fmaxf(x01 + pv.y, 0.f) * w1
          + fmaxf(x02 + pv.z, 0.f) * w2v + fmaxf(x03 + pv.w, 0.f) * w3;
      a1 += fmaxf(x10 + pv.x, 0.f) * w0 + fmaxf(x11 + pv.y, 0.f) * w1
          + fmaxf(x12 + pv.z, 0.f) * w2v + fmaxf(x13 + pv.w, 0.f) * w3;
    }
    acc0[m] = a0 + b2[m]; acc1[m] = a1 + b2[m];
  }

  float q2c = charge2[col], v2 = valid2[col], n2 = nm2[col];
  float vc2 = vdw_coeff[0] * vdw_coeff[0];
  float ec_sum = 0.f, ev_sum = 0.f;
#pragma unroll
  for (int ti = 0; ti < 2; ++ti) {
    const float* am = ti ? acc1 : acc0;
    int gi = r0 + ti;
    int pidx = gi * NN + j;
    float dx = dmv[pidx * 3 + 0], dy = dmv[pidx * 3 + 1], dz = dmv[pidx * 3 + 2];
    float dm = sqrtf(dx * dx + dy * dy + dz * dz + 1e-10f);
    if (dm < 0.5f) dm = 1e10f;
    // coulomb
    float cA = sigmoidf_(am[0]);
    float cN = sigmoidf_(am[1]) * 2.f + 1.f;
    float e_c = cA * charge1[gi] * q2c * __powf(1.f / dm, cN);
    e_c *= valid1[gi] * v2;
    e_c = fminf(fmaxf(e_c, -100.f), 100.f);
    ec_sum += e_c;
    // vdw
    float vA = (sigmoidf_(am[2]) * 0.6f + 0.7f) * vc2 * veps[pidx];
    float vB = tanhf_(am[3]) * 0.6f + 0.7f;
    float vN = sigmoidf_(am[4]) * 2.f + 5.f;
    float dm0 = vsig[pidx] * vB;
    if (dm0 < 1e-4f) dm0 = 1.f;
    float rr = __powf(dm0 / dm, vN);
    float e_v = vA * (rr * rr - 2.f * rr);
    e_v *= nm1[gi] * n2;
    e_v = fminf(e_v, 100.f);
    ev_sum += e_v;
  }
#pragma unroll
  for (int off = 32; off > 0; off >>= 1) {
    ec_sum += __shfl_down(ec_sum, off);
    ev_sum += __shfl_down(ev_sum, off);
  }
  __shared__ float rec[6], rev[6];
  if ((tid & 63) == 0) { rec[tid >> 6] = ec_sum; rev[tid >> 6] = ev_sum; }
  __syncthreads();
  if (tid == 0) {
    float a = 0.f, c = 0.f;
#pragma unroll
    for (int w = 0; w < 6; ++w) { a += rec[w]; c += rev[w]; }
    atomicAdd(&out[b * 4 + 0], a);
    atomicAdd(&out[b * 4 + 1], c);
  }
}

// ---------------------------------------------------------------- intercept finish
__global__ __launch_bounds__(256) void k_intercept_fin(
    const float* __restrict__ ws_int, const float* __restrict__ W1,
    const float* __restrict__ b1, const float* __restrict__ W2,
    const float* __restrict__ b2, float* __restrict__ out) {
  int b = blockIdx.x;
  int tid = threadIdx.x, c = tid & 127, kh = tid >> 7;
  __shared__ float hsf[DD];
  __shared__ float ph[2][DD];
  __shared__ float redw[2];
  if (tid < DD)
    hsf[tid] = ws_int[(b * 4 + 0) * DD + tid] + ws_int[(b * 4 + 1) * DD + tid]
             + ws_int[(b * 4 + 2) * DD + tid] + ws_int[(b * 4 + 3) * DD + tid];
  __syncthreads();
  float acc = 0.f;
  const float* Wp = W1 + (kh * 64) * HH + c;
#pragma unroll 4
  for (int k = 0; k < 64; ++k) acc += hsf[kh * 64 + k] * Wp[k * HH];
  ph[kh][c] = acc;
  __syncthreads();
  if (tid < DD) {
    float hid = fmaxf(ph[0][tid] + ph[1][tid] + b1[tid], 0.f);
    float v = hid * W2[tid];
#pragma unroll
    for (int off = 32; off > 0; off >>= 1) v += __shfl_down(v, off);
    if ((tid & 63) == 0) redw[tid >> 6] = v;
  }
  __syncthreads();
  if (tid == 0) out[b * 4 + 3] = redw[0] + redw[1] + b2[0];
}

// ---------------------------------------------------------------- launch
extern "C" void kernel_launch(void* const* d_in, const int* in_sizes, int n_in,
                              void* d_out, int out_size, void* d_ws, size_t ws_size,
                              hipStream_t stream) {
  (void)in_sizes; (void)n_in; (void)out_size; (void)ws_size;
  const float* h1         = (const float*)d_in[0];
  const float* h2         = (const float*)d_in[1];
  const float* adj1       = (const float*)d_in[2];
  const float* dmv        = (const float*)d_in[3];
  const float* charge1    = (const float*)d_in[4];
  const float* charge2    = (const float*)d_in[5];
  const float* veps       = (const float*)d_in[6];
  const float* vsig       = (const float*)d_in[7];
  const float* delta_uff  = (const float*)d_in[8];
  const float* valid1     = (const float*)d_in[9];
  const float* valid2     = (const float*)d_in[10];
  const float* nm1        = (const float*)d_in[11];
  const float* nm2        = (const float*)d_in[12];
  const float* node_W     = (const float*)d_in[13];
  const float* gat_W      = (const float*)d_in[14];
  const float* gat_Wb     = (const float*)d_in[15];
  const float* gat_A      = (const float*)d_in[16];
  const float* gat_gW     = (const float*)d_in[17];
  const float* gat_gb     = (const float*)d_in[18];
  const float* pW1        = (const float*)d_in[19];
  const float* pb1        = (const float*)d_in[20];
  const float* pW2        = (const float*)d_in[21];
  const float* pb2        = (const float*)d_in[22];
  const float* vdw_coeff  = (const float*)d_in[23];
  const float* duff_coeff = (const float*)d_in[24];
  const float* iW1        = (const float*)d_in[25];
  const float* ib1        = (const float*)d_in[26];
  const float* iW2        = (const float*)d_in[27];
  const float* ib2        = (const float*)d_in[28];
  float* out = (float*)d_out;

  float* ws = (float*)d_ws;
  const int RN = BB * NN * DD;  // 98304
  float* h1gA   = ws;
  float* h1gB   = h1gA + RN;
  float* h2g    = h1gB + RN;
  float* hbuf   = h2g + RN;
  float* hAbuf  = hbuf + RN;
  float* hTbuf  = hAbuf + RN;
  float* hATbuf = hTbuf + RN;
  float* att    = hATbuf + RN;              // BB*NN*NN row-major
  float* p1     = att + BB * NN * NN;       // BB*NN*5*HH
  float* p2q    = p1 + BB * NN * 5 * HH;    // 5*(HH/4)*PCOLS float4 (same size)
  float* ws_int = p2q + 5 * HH * PCOLS;     // 8*128

  k_embed<<<dim3(2 * BB * NN / 2), dim3(256), 0, stream>>>(h1, h2, node_W, h1gA, h2g);

  float* cur = h1gA;
  float* nxt = h1gB;
  for (int l = 0; l < 3; ++l) {
    k_gat_hhA<<<dim3(BB * NN / 2), dim3(256), 0, stream>>>(
        cur, gat_W + l * DD * DD, gat_Wb + l * DD, gat_A + l * DD * DD,
        hbuf, hAbuf, hTbuf, hATbuf);
    k_gat_att<<<dim3(BB * NN / 2), dim3(384), 0, stream>>>(
        hbuf, hAbuf, hTbuf, hATbuf, adj1, att);
    k_gat_out<<<dim3(BB * NN / 2), dim3(256), 0, stream>>>(
        cur, hbuf, att, gat_gW + l * 2 * DD, gat_gb + l, nxt);
    float* t = cur; cur = nxt; nxt = t;
  }
  const float* h1gF = cur;

  k_pair_proj<<<dim3((2 * BB * NN / 16) * 5), dim3(256), 0, stream>>>(
      h1gF, h2g, pW1, pb1, delta_uff, duff_coeff, p1, p2q, out);
  k_pair_energy<<<dim3(384 + 8), dim3(384), 0, stream>>>(
      p1, p2q, pW2, pb2, dmv, charge1, charge2, veps, vsig,
      valid1, valid2, nm1, nm2, vdw_coeff, h1gF, ws_int, out);
  k_intercept_fin<<<dim3(BB), dim3(256), 0, stream>>>(ws_int, iW1, ib1, iW2, ib2, out);
}